// Round 1
// baseline (6689.326 us; speedup 1.0000x reference)
//
#include <hip/hip_runtime.h>
#include <hip/hip_bf16.h>

#define B_ 2
#define S_ 2048
#define HID_ 2048
#define H_ 16
#define KVH_ 8
#define D_ 128
#define G_ 2
#define EPS_ 1e-6f
#define SCALE_ 0.08838834764831845f

typedef __hip_bfloat16 bf16;

__device__ inline float to_f(float x) { return x; }
__device__ inline float to_f(bf16 x) { return __bfloat162float(x); }
__device__ inline void store_c(float* p, float v) { *p = v; }
__device__ inline void store_c(bf16* p, float v) { *p = __float2bfloat16(v); }

// ---------------------------------------------------------------------------
// Tiled GEMM: C[M,N] = A[M,K] @ W[K,N].  A: fp32 or bf16. C: fp32 or bf16.
// 64x64 tile, 256 threads, 4x4 per thread, BK=16.
// ---------------------------------------------------------------------------
template <typename AT, typename CT>
__global__ __launch_bounds__(256) void gemm_tiled(const AT* __restrict__ A,
                                                  const float* __restrict__ W,
                                                  CT* __restrict__ C,
                                                  int M, int N, int K) {
    __shared__ float As[64][17];
    __shared__ float Bs[16][65];
    const int tid = threadIdx.x;
    const int row0 = blockIdx.y * 64;
    const int col0 = blockIdx.x * 64;
    const int tx = tid & 15, ty = tid >> 4;

    float acc[4][4];
#pragma unroll
    for (int i = 0; i < 4; i++)
#pragma unroll
        for (int j = 0; j < 4; j++) acc[i][j] = 0.f;

    for (int kt = 0; kt < K; kt += 16) {
        {
            const int k = tid & 15, r = tid >> 4;
#pragma unroll
            for (int i = 0; i < 4; i++)
                As[r + i * 16][k] = to_f(A[(size_t)(row0 + r + i * 16) * K + kt + k]);
        }
        {
            const int c = tid & 63, kk = tid >> 6;
#pragma unroll
            for (int i = 0; i < 4; i++)
                Bs[kk + i * 4][c] = W[(size_t)(kt + kk + i * 4) * N + col0 + c];
        }
        __syncthreads();
#pragma unroll
        for (int k = 0; k < 16; k++) {
            float a[4], b[4];
#pragma unroll
            for (int i = 0; i < 4; i++) a[i] = As[ty * 4 + i][k];
#pragma unroll
            for (int j = 0; j < 4; j++) b[j] = Bs[k][tx * 4 + j];
#pragma unroll
            for (int i = 0; i < 4; i++)
#pragma unroll
                for (int j = 0; j < 4; j++) acc[i][j] += a[i] * b[j];
        }
        __syncthreads();
    }
#pragma unroll
    for (int i = 0; i < 4; i++)
#pragma unroll
        for (int j = 0; j < 4; j++)
            store_c(&C[(size_t)(row0 + ty * 4 + i) * N + col0 + tx * 4 + j], acc[i][j]);
}

// ---------------------------------------------------------------------------
// Per-(b,s,head) RMSNorm + RoPE.  Optionally also transposes V.
//   src element:  src[((b*S+s)*NH + h)*chanStride + d]   (bf16)
//   dst element:  dst[((b*NH + h)*S + s)*D + d]          (bf16)
// grid = B*S*NH blocks, 128 threads (one per d).
// ---------------------------------------------------------------------------
__global__ __launch_bounds__(128) void norm_rope(const bf16* __restrict__ src,
                                                 const float* __restrict__ normw,
                                                 const float* __restrict__ cosb,
                                                 const float* __restrict__ sinb,
                                                 bf16* __restrict__ dst,
                                                 const bf16* __restrict__ vsrc,
                                                 bf16* __restrict__ vdst,
                                                 int NH, int chanStride) {
    const int idx = blockIdx.x;
    const int h = idx % NH;
    const int s = (idx / NH) % S_;
    const int b = idx / (NH * S_);
    const int d = threadIdx.x;

    const size_t src_i = ((size_t)(b * S_ + s) * NH + h) * chanStride + d;
    const size_t dst_i = (((size_t)b * NH + h) * S_ + s) * D_ + d;

    float x = __bfloat162float(src[src_i]);

    // mean of squares over 128 lanes (2 waves)
    float sq = x * x;
#pragma unroll
    for (int o = 32; o > 0; o >>= 1) sq += __shfl_down(sq, o);
    __shared__ float red[2];
    __shared__ float sh[128];
    if ((d & 63) == 0) red[d >> 6] = sq;
    __syncthreads();
    const float var = (red[0] + red[1]) * (1.f / 128.f);
    const float xn = x * rsqrtf(var + EPS_) * normw[d];
    sh[d] = xn;
    __syncthreads();
    const float rot = (d < 64) ? -sh[d + 64] : sh[d - 64];

    const size_t cs_i = ((size_t)b * S_ + s) * D_ + d;
    const float o = xn * cosb[cs_i] + rot * sinb[cs_i];
    dst[dst_i] = __float2bfloat16(o);

    if (vsrc != nullptr) {
        const size_t v_i = ((size_t)(b * S_ + s) * NH + h) * D_ + d;
        vdst[dst_i] = vsrc[v_i];
    }
}

// ---------------------------------------------------------------------------
// Causal GQA flash attention + sigmoid-gate epilogue.
// grid = (S/32, B*H), 256 threads. 32 q-rows per block, 32-key tiles.
// q/k/v in (B, NH, S, D) bf16.  gate read from mixedq.  out -> attg (B,S,H*D).
// ---------------------------------------------------------------------------
__global__ __launch_bounds__(256) void flash_attn(const bf16* __restrict__ qro,
                                                  const bf16* __restrict__ kro,
                                                  const bf16* __restrict__ vt,
                                                  const bf16* __restrict__ mixedq,
                                                  bf16* __restrict__ attg) {
    const int qt = blockIdx.x;
    const int bh = blockIdx.y;
    const int b = bh / H_, h = bh % H_;
    const int kvh = h / G_;
    const int q0 = qt * 32;

    const bf16* qbase = qro + ((size_t)(b * H_ + h) * S_) * D_;
    const bf16* kbase = kro + ((size_t)(b * KVH_ + kvh) * S_) * D_;
    const bf16* vbase = vt + ((size_t)(b * KVH_ + kvh) * S_) * D_;

    __shared__ bf16 Qs[32][D_];
    __shared__ bf16 Ks[32][D_];
    __shared__ bf16 Vs[32][D_];
    __shared__ float P[32][33];
    __shared__ float mrow[32], lrow[32], corr[32];

    const int tid = threadIdx.x;

    for (int i = tid; i < 32 * D_; i += 256) {
        const int r = i >> 7, d = i & 127;
        Qs[r][d] = qbase[(size_t)(q0 + r) * D_ + d];
    }
    if (tid < 32) {
        mrow[tid] = -1e30f;
        lrow[tid] = 0.f;
    }

    float acc[16];
#pragma unroll
    for (int i = 0; i < 16; i++) acc[i] = 0.f;
    const int r_own = tid >> 3;
    const int c0 = (tid & 7) * 16;

    const int nkt = q0 / 32 + 1;
    for (int kt = 0; kt < nkt; kt++) {
        __syncthreads();
        for (int i = tid; i < 32 * D_; i += 256) {
            const int r = i >> 7, d = i & 127;
            Ks[r][d] = kbase[(size_t)(kt * 32 + r) * D_ + d];
            Vs[r][d] = vbase[(size_t)(kt * 32 + r) * D_ + d];
        }
        __syncthreads();

        // scores: each thread does rows r = tid&31, cols (tid>>5)*4 .. +3
        {
            const int r = tid & 31;
            const int j0 = (tid >> 5) * 4;
#pragma unroll
            for (int jj = 0; jj < 4; jj++) {
                const int j = j0 + jj;
                float s = 0.f;
                for (int d = 0; d < D_; d++)
                    s += __bfloat162float(Qs[r][d]) * __bfloat162float(Ks[j][d]);
                s *= SCALE_;
                if (kt * 32 + j > q0 + r) s = -1e30f;
                P[r][j] = s;
            }
        }
        __syncthreads();

        // online softmax, one thread per row
        if (tid < 32) {
            const float m_old = mrow[tid];
            float mx = m_old;
            for (int j = 0; j < 32; j++) mx = fmaxf(mx, P[tid][j]);
            const float c = __expf(m_old - mx);
            float lsum = 0.f;
            for (int j = 0; j < 32; j++) {
                const float p = __expf(P[tid][j] - mx);
                P[tid][j] = p;
                lsum += p;
            }
            mrow[tid] = mx;
            lrow[tid] = lrow[tid] * c + lsum;
            corr[tid] = c;
        }
        __syncthreads();

        // rescale + PV
        const float c = corr[r_own];
#pragma unroll
        for (int i = 0; i < 16; i++) acc[i] *= c;
        for (int j = 0; j < 32; j++) {
            const float p = P[r_own][j];
#pragma unroll
            for (int i = 0; i < 16; i++)
                acc[i] += p * __bfloat162float(Vs[j][c0 + i]);
        }
    }
    __syncthreads();

    // epilogue: 1/l, sigmoid gate, write (B,S,H*D)
    const float linv = 1.f / lrow[r_own];
    const int s_q = q0 + r_own;
    const bf16* gatep = mixedq + (((size_t)(b * S_ + s_q) * H_ + h) * 256 + 128);
    bf16* outp = attg + (((size_t)(b * S_ + s_q) * H_ + h) * 128);
#pragma unroll
    for (int i = 0; i < 16; i++) {
        const float g = __bfloat162float(gatep[c0 + i]);
        const float o = acc[i] * linv * (1.f / (1.f + __expf(-g)));
        outp[c0 + i] = __float2bfloat16(o);
    }
}

// ---------------------------------------------------------------------------
extern "C" void kernel_launch(void* const* d_in, const int* in_sizes, int n_in,
                              void* d_out, int out_size, void* d_ws, size_t ws_size,
                              hipStream_t stream) {
    const float* hs = (const float*)d_in[0];
    const float* cosb = (const float*)d_in[1];
    const float* sinb = (const float*)d_in[2];
    const float* Wq = (const float*)d_in[3];
    const float* Wk = (const float*)d_in[4];
    const float* Wv = (const float*)d_in[5];
    const float* Wo = (const float*)d_in[6];
    const float* qnw = (const float*)d_in[7];
    const float* knw = (const float*)d_in[8];
    float* out = (float*)d_out;

    bf16* ws = (bf16*)d_ws;
    bf16* mixedq = ws;                    // B*S*H*2D        = 16777216
    bf16* kraw = mixedq + 16777216;       // B*S*KVH*D       =  4194304
    bf16* vraw = kraw + 4194304;          //                 =  4194304
    bf16* qro = vraw + 4194304;           // B*H*S*D         =  8388608
    bf16* kro = qro + 8388608;            // B*KVH*S*D       =  4194304
    bf16* vt = kro + 4194304;             //                 =  4194304
    bf16* attg = vt + 4194304;            // B*S*H*D         =  8388608

    const int M = B_ * S_;

    // QKV projections
    gemm_tiled<float, bf16><<<dim3(4096 / 64, M / 64), 256, 0, stream>>>(hs, Wq, mixedq, M, 4096, HID_);
    gemm_tiled<float, bf16><<<dim3(1024 / 64, M / 64), 256, 0, stream>>>(hs, Wk, kraw, M, 1024, HID_);
    gemm_tiled<float, bf16><<<dim3(1024 / 64, M / 64), 256, 0, stream>>>(hs, Wv, vraw, M, 1024, HID_);

    // RMSNorm + RoPE (+ V transpose)
    norm_rope<<<dim3(B_ * S_ * H_), 128, 0, stream>>>(mixedq, qnw, cosb, sinb, qro,
                                                      nullptr, nullptr, H_, 2 * D_);
    norm_rope<<<dim3(B_ * S_ * KVH_), 128, 0, stream>>>(kraw, knw, cosb, sinb, kro,
                                                        vraw, vt, KVH_, D_);

    // causal GQA attention + gate
    flash_attn<<<dim3(S_ / 32, B_ * H_), 256, 0, stream>>>(qro, kro, vt, mixedq, attg);

    // output projection
    gemm_tiled<bf16, float><<<dim3(HID_ / 64, M / 64), 256, 0, stream>>>(attg, Wo, out, M, HID_, 2048);
}

// Round 3
// 514.989 us; speedup vs baseline: 12.9893x; 12.9893x over previous
//
#include <hip/hip_runtime.h>
#include <hip/hip_bf16.h>

#define B_ 2
#define S_ 2048
#define HID_ 2048
#define H_ 16
#define KVH_ 8
#define D_ 128
#define G_ 2
#define EPS_ 1e-6f
#define SCALE_ 0.08838834764831845f

typedef __hip_bfloat16 bf16;
typedef __attribute__((ext_vector_type(8))) short s8v;   // 8 bf16 = 4 VGPR
typedef __attribute__((ext_vector_type(4))) float f4v;   // MFMA C/D

__device__ __forceinline__ unsigned short f2b(float f) {
    __hip_bfloat16 h = __float2bfloat16(f);
    return *reinterpret_cast<unsigned short*>(&h);
}
__device__ __forceinline__ float b2f(short u) {
    unsigned int x = ((unsigned int)(unsigned short)u) << 16;
    return __builtin_bit_cast(float, x);
}

__device__ __forceinline__ f4v MFMA(s8v a, s8v b, f4v c) {
    return __builtin_amdgcn_mfma_f32_16x16x32_bf16(a, b, c, 0, 0, 0);
}

__device__ __forceinline__ void gl_lds16(const void* g, void* l) {
    __builtin_amdgcn_global_load_lds(
        (const __attribute__((address_space(1))) void*)g,
        (__attribute__((address_space(3))) void*)l, 16, 0, 0);
}

__device__ __forceinline__ void cstore(float* p, float v) { *p = v; }
__device__ __forceinline__ void cstore(short* p, float v) { *p = (short)f2b(v); }

// ---------------------------------------------------------------------------
// fp32 -> bf16 bulk convert (vectorized)
// ---------------------------------------------------------------------------
__global__ __launch_bounds__(256) void f2bf_kernel(const float* __restrict__ in,
                                                   short* __restrict__ out, int n4) {
    int i = blockIdx.x * 256 + threadIdx.x;
    if (i >= n4) return;
    const float4 v = *(const float4*)(in + (size_t)i * 4);
    ushort4 o;
    o.x = f2b(v.x); o.y = f2b(v.y); o.z = f2b(v.z); o.w = f2b(v.w);
    *(ushort4*)(out + (size_t)i * 4) = o;
}

// ---------------------------------------------------------------------------
// W[K][N] fp32  ->  Wt[N][K] bf16   (32x32 LDS tile transpose)
// ---------------------------------------------------------------------------
__global__ __launch_bounds__(256) void transpose_conv(const float* __restrict__ in,
                                                      short* __restrict__ out,
                                                      int K, int N) {
    __shared__ short t[32][33];
    const int n0 = blockIdx.x * 32, k0 = blockIdx.y * 32;
    const int tx = threadIdx.x, ty = threadIdx.y;
#pragma unroll
    for (int j = 0; j < 4; j++) {
        const int r = ty + j * 8;
        t[r][tx] = (short)f2b(in[(size_t)(k0 + r) * N + n0 + tx]);
    }
    __syncthreads();
#pragma unroll
    for (int j = 0; j < 4; j++) {
        const int r = ty + j * 8;
        out[(size_t)(n0 + r) * K + k0 + tx] = t[tx][r];
    }
}

// ---------------------------------------------------------------------------
// V transpose per head: vraw[B][S][KVH][D] -> vt[(b*KVH+kvh)][D][S]
// ---------------------------------------------------------------------------
__global__ __launch_bounds__(256) void transpose_v(const short* __restrict__ in,
                                                   short* __restrict__ out) {
    __shared__ short t[32][33];
    const int s0 = blockIdx.x * 32, d0 = blockIdx.y * 32, bk = blockIdx.z;
    const int b = bk / KVH_, kvh = bk % KVH_;
    const short* ip = in + (size_t)b * S_ * KVH_ * D_ + kvh * D_;
    const int tx = threadIdx.x, ty = threadIdx.y;
#pragma unroll
    for (int j = 0; j < 4; j++) {
        const int r = ty + j * 8;
        t[r][tx] = ip[(size_t)(s0 + r) * (KVH_ * D_) + d0 + tx];
    }
    __syncthreads();
#pragma unroll
    for (int j = 0; j < 4; j++) {
        const int r = ty + j * 8;
        out[((size_t)bk * D_ + d0 + r) * S_ + s0 + tx] = t[tx][r];
    }
}

// ---------------------------------------------------------------------------
// MFMA GEMM (B^T form): C[M,N] = A[M,K] @ Bt[N,K]^T, bf16 in, fp32 acc.
// 128x128 tile, BK=32, 4 waves (2x2), 4x4 frags of 16x16x32 per wave.
// ---------------------------------------------------------------------------
template <typename CT>
__global__ __launch_bounds__(256) void gemm_bt(const short* __restrict__ A,
                                               const short* __restrict__ Bt,
                                               CT* __restrict__ C,
                                               int M, int N, int K) {
    __shared__ __align__(16) short As[128][32];
    __shared__ __align__(16) short Bs[128][32];
    const int tid = threadIdx.x;
    const int w = tid >> 6, l = tid & 63;
    const int lr = l & 15, g = l >> 4;
    const int row0 = blockIdx.y * 128, col0 = blockIdx.x * 128;
    const int wr = w >> 1, wc = w & 1;

    f4v acc[4][4];
#pragma unroll
    for (int i = 0; i < 4; i++)
#pragma unroll
        for (int j = 0; j < 4; j++) acc[i][j] = (f4v)0.f;

    const int srow = (l >> 2);       // row within 16-row staging chunk
    const int sslot = (l & 3);       // 16B slot within 64B row

    for (int kt = 0; kt < K; kt += 32) {
        __syncthreads();
#pragma unroll
        for (int i = 0; i < 2; i++) {
            const int rb = (w * 2 + i) * 16;
            gl_lds16(A + ((size_t)(row0 + rb + srow) * K + kt + sslot * 8), &As[rb][0]);
            gl_lds16(Bt + ((size_t)(col0 + rb + srow) * K + kt + sslot * 8), &Bs[rb][0]);
        }
        __syncthreads();
        s8v a[4], b[4];
#pragma unroll
        for (int mi = 0; mi < 4; mi++)
            a[mi] = *(const s8v*)&As[wr * 64 + mi * 16 + lr][g * 8];
#pragma unroll
        for (int ni = 0; ni < 4; ni++)
            b[ni] = *(const s8v*)&Bs[wc * 64 + ni * 16 + lr][g * 8];
#pragma unroll
        for (int mi = 0; mi < 4; mi++)
#pragma unroll
            for (int ni = 0; ni < 4; ni++)
                acc[mi][ni] = MFMA(a[mi], b[ni], acc[mi][ni]);
    }

#pragma unroll
    for (int mi = 0; mi < 4; mi++)
#pragma unroll
        for (int ni = 0; ni < 4; ni++) {
            const int row = row0 + wr * 64 + mi * 16 + g * 4;
            const int col = col0 + wc * 64 + ni * 16 + lr;
#pragma unroll
            for (int j = 0; j < 4; j++)
                cstore(&C[(size_t)(row + j) * N + col], acc[mi][ni][j]);
        }
}

// ---------------------------------------------------------------------------
// Per-(b,s,head) RMSNorm + RoPE.
// ---------------------------------------------------------------------------
__global__ __launch_bounds__(128) void norm_rope(const bf16* __restrict__ src,
                                                 const float* __restrict__ normw,
                                                 const float* __restrict__ cosb,
                                                 const float* __restrict__ sinb,
                                                 bf16* __restrict__ dst,
                                                 int NH, int chanStride) {
    const int idx = blockIdx.x;
    const int h = idx % NH;
    const int s = (idx / NH) % S_;
    const int b = idx / (NH * S_);
    const int d = threadIdx.x;

    const size_t src_i = ((size_t)(b * S_ + s) * NH + h) * chanStride + d;
    const size_t dst_i = (((size_t)b * NH + h) * S_ + s) * D_ + d;

    float x = __bfloat162float(src[src_i]);
    float sq = x * x;
#pragma unroll
    for (int o = 32; o > 0; o >>= 1) sq += __shfl_down(sq, o);
    __shared__ float red[2];
    __shared__ float sh[128];
    if ((d & 63) == 0) red[d >> 6] = sq;
    __syncthreads();
    const float var = (red[0] + red[1]) * (1.f / 128.f);
    const float xn = x * rsqrtf(var + EPS_) * normw[d];
    sh[d] = xn;
    __syncthreads();
    const float rot = (d < 64) ? -sh[d + 64] : sh[d - 64];
    const size_t cs_i = ((size_t)b * S_ + s) * D_ + d;
    dst[dst_i] = __float2bfloat16(xn * cosb[cs_i] + rot * sinb[cs_i]);
}

// ---------------------------------------------------------------------------
// MFMA causal GQA flash attention + sigmoid gate.
// grid = (S/64, B*H), 256 thr. 4 waves x 16 q-rows; KV tile = 64.
// K_lds/V_lds staged via global_load_lds with XOR slot-swizzle (slot ^= r&7),
// pre-swizzled global source (both-sides rule).
// ---------------------------------------------------------------------------
__global__ __launch_bounds__(256) void flash_mfma(const short* __restrict__ qro,
                                                  const short* __restrict__ kro,
                                                  const short* __restrict__ vt,
                                                  const short* __restrict__ mixedq,
                                                  short* __restrict__ attg) {
    __shared__ __align__(16) short Ks[64][128];   // [key][d], slot-swizzled
    __shared__ __align__(16) short Vs[128][64];   // [d][key], slot-swizzled
    __shared__ __align__(16) short Pl[4][16][80]; // per-wave P transpose buffer

    const int tid = threadIdx.x;
    const int w = tid >> 6, l = tid & 63;
    const int lr = l & 15, g = l >> 4;
    const int qt = (int)gridDim.x - 1 - (int)blockIdx.x;  // heavy blocks first
    const int bh = blockIdx.y;
    const int b = bh >> 4, h = bh & 15;
    const int kvh = h >> 1;
    const int q0 = qt * 64;
    const int qw0 = q0 + w * 16;

    const short* qbase = qro + (size_t)(b * H_ + h) * S_ * D_;
    const short* kbase = kro + (size_t)(b * KVH_ + kvh) * S_ * D_;
    const short* vbase = vt + (size_t)(b * KVH_ + kvh) * D_ * S_;

    // Q fragments held in registers for the whole kernel
    s8v qa[4];
#pragma unroll
    for (int kc = 0; kc < 4; kc++)
        qa[kc] = *(const s8v*)(qbase + (size_t)(qw0 + lr) * D_ + kc * 32 + g * 8);

    f4v oacc[8];
#pragma unroll
    for (int i = 0; i < 8; i++) oacc[i] = (f4v)0.f;
    float m[4] = {-3e38f, -3e38f, -3e38f, -3e38f};
    float lsum[4] = {0.f, 0.f, 0.f, 0.f};

    const int nkt = qt + 1;
    for (int kt = 0; kt < nkt; kt++) {
        const int kb0 = kt * 64;
        __syncthreads();
        // ---- stage K (64x128) and V^T (128x64), swizzled source ----
#pragma unroll
        for (int i = 0; i < 4; i++) {
            const int li = w * 4 + i;
            {
                const int r = li * 4 + (l >> 4);
                const int sg = (l & 15) ^ (r & 7);
                gl_lds16(kbase + (size_t)(kb0 + r) * D_ + sg * 8, &Ks[li * 4][0]);
            }
            {
                const int r = li * 8 + (l >> 3);
                const int sg = (l & 7) ^ (r & 7);
                gl_lds16(vbase + (size_t)r * S_ + kb0 + sg * 8, &Vs[li * 8][0]);
            }
        }
        __syncthreads();

        // ---- QK^T: S[16 q][64 keys] ----
        f4v sacc[4];
#pragma unroll
        for (int ni = 0; ni < 4; ni++) sacc[ni] = (f4v)0.f;
#pragma unroll
        for (int ni = 0; ni < 4; ni++) {
            const int r = ni * 16 + lr;
#pragma unroll
            for (int kc = 0; kc < 4; kc++) {
                const int ph = (kc * 4 + g) ^ (r & 7);
                const s8v kb = *(const s8v*)&Ks[r][ph * 8];
                sacc[ni] = MFMA(qa[kc], kb, sacc[ni]);
            }
        }

        // ---- online softmax (lane-group reductions over 16 lanes) ----
        const bool masked = (kt == qt);
        float p[4][4], tmax[4];
#pragma unroll
        for (int j = 0; j < 4; j++) {
            float v0 = -3e38f;
#pragma unroll
            for (int ni = 0; ni < 4; ni++) {
                float sc = sacc[ni][j] * SCALE_;
                if (masked && (kb0 + ni * 16 + lr > qw0 + g * 4 + j)) sc = -3e38f;
                p[ni][j] = sc;
                v0 = fmaxf(v0, sc);
            }
            tmax[j] = v0;
        }
#pragma unroll
        for (int off = 1; off < 16; off <<= 1)
#pragma unroll
            for (int j = 0; j < 4; j++)
                tmax[j] = fmaxf(tmax[j], __shfl_xor(tmax[j], off));
        float cj[4], psum[4];
#pragma unroll
        for (int j = 0; j < 4; j++) {
            const float mn = fmaxf(m[j], tmax[j]);
            cj[j] = __expf(m[j] - mn);
            m[j] = mn;
            float ps = 0.f;
#pragma unroll
            for (int ni = 0; ni < 4; ni++) {
                const float e = __expf(p[ni][j] - mn);
                p[ni][j] = e;
                ps += e;
            }
            psum[j] = ps;
        }
#pragma unroll
        for (int off = 1; off < 16; off <<= 1)
#pragma unroll
            for (int j = 0; j < 4; j++) psum[j] += __shfl_xor(psum[j], off);
#pragma unroll
        for (int j = 0; j < 4; j++) lsum[j] = lsum[j] * cj[j] + psum[j];
#pragma unroll
        for (int di = 0; di < 8; di++)
#pragma unroll
            for (int j = 0; j < 4; j++) oacc[di][j] *= cj[j];

        // ---- P -> bf16 via LDS transpose (wave-private) ----
#pragma unroll
        for (int ni = 0; ni < 4; ni++)
#pragma unroll
            for (int j = 0; j < 4; j++)
                Pl[w][g * 4 + j][ni * 16 + lr] = (short)f2b(p[ni][j]);

        // ---- PV: O += P[16x64] @ V[64x128] ----
#pragma unroll
        for (int kk = 0; kk < 2; kk++) {
            const s8v pa = *(const s8v*)&Pl[w][lr][kk * 32 + g * 8];
#pragma unroll
            for (int di = 0; di < 8; di++) {
                const int r = di * 16 + lr;
                const int ph = (kk * 4 + g) ^ (r & 7);
                const s8v vb = *(const s8v*)&Vs[r][ph * 8];
                oacc[di] = MFMA(pa, vb, oacc[di]);
            }
        }
    }

    // ---- epilogue: 1/l, sigmoid gate, store ----
    float linv[4];
#pragma unroll
    for (int j = 0; j < 4; j++) linv[j] = 1.f / lsum[j];
#pragma unroll
    for (int di = 0; di < 8; di++) {
        const int d = di * 16 + lr;
#pragma unroll
        for (int j = 0; j < 4; j++) {
            const int q = qw0 + g * 4 + j;
            const float gate = b2f(mixedq[((size_t)(b * S_ + q) * H_ + h) * 256 + 128 + d]);
            const float o = oacc[di][j] * linv[j] * (1.f / (1.f + __expf(-gate)));
            attg[((size_t)(b * S_ + q) * H_ + h) * 128 + d] = (short)f2b(o);
        }
    }
}

// ---------------------------------------------------------------------------
extern "C" void kernel_launch(void* const* d_in, const int* in_sizes, int n_in,
                              void* d_out, int out_size, void* d_ws, size_t ws_size,
                              hipStream_t stream) {
    const float* hs = (const float*)d_in[0];
    const float* cosb = (const float*)d_in[1];
    const float* sinb = (const float*)d_in[2];
    const float* Wq = (const float*)d_in[3];
    const float* Wk = (const float*)d_in[4];
    const float* Wv = (const float*)d_in[5];
    const float* Wo = (const float*)d_in[6];
    const float* qnw = (const float*)d_in[7];
    const float* knw = (const float*)d_in[8];
    float* out = (float*)d_out;

    short* ws = (short*)d_ws;
    short* hsb    = ws;              // 8388608, reused as attg
    short* Wqt    = ws + 8388608;    // 8388608, reused as qro
    short* Wkt    = ws + 16777216;   // 2097152, with Wvt reused as kro
    short* Wvt    = ws + 18874368;   // 2097152
    short* Wot    = ws + 20971520;   // 4194304
    short* mixedq = ws + 25165824;   // 16777216
    short* kraw   = ws + 41943040;   // 4194304, reused as vt
    short* vraw   = ws + 46137344;   // 4194304
    short* attg   = hsb;
    short* qro    = Wqt;
    short* kro    = Wkt;
    short* vtb    = kraw;

    const int M = B_ * S_;
    const dim3 t32x8(32, 8, 1);

    // bf16 conversions / transposes
    f2bf_kernel<<<8192, 256, 0, stream>>>(hs, hsb, 2097152);
    transpose_conv<<<dim3(4096 / 32, HID_ / 32), t32x8, 0, stream>>>(Wq, Wqt, HID_, 4096);
    transpose_conv<<<dim3(1024 / 32, HID_ / 32), t32x8, 0, stream>>>(Wk, Wkt, HID_, 1024);
    transpose_conv<<<dim3(1024 / 32, HID_ / 32), t32x8, 0, stream>>>(Wv, Wvt, HID_, 1024);
    transpose_conv<<<dim3(2048 / 32, 2048 / 32), t32x8, 0, stream>>>(Wo, Wot, 2048, 2048);

    // QKV projections (bf16 MFMA)
    gemm_bt<short><<<dim3(4096 / 128, M / 128), 256, 0, stream>>>(hsb, Wqt, mixedq, M, 4096, HID_);
    gemm_bt<short><<<dim3(1024 / 128, M / 128), 256, 0, stream>>>(hsb, Wkt, kraw, M, 1024, HID_);
    gemm_bt<short><<<dim3(1024 / 128, M / 128), 256, 0, stream>>>(hsb, Wvt, vraw, M, 1024, HID_);

    // RMSNorm + RoPE
    norm_rope<<<dim3(B_ * S_ * H_), 128, 0, stream>>>((const bf16*)mixedq, qnw, cosb, sinb,
                                                      (bf16*)qro, H_, 2 * D_);
    norm_rope<<<dim3(B_ * S_ * KVH_), 128, 0, stream>>>((const bf16*)kraw, knw, cosb, sinb,
                                                        (bf16*)kro, KVH_, D_);

    // V transpose to [head][D][S]
    transpose_v<<<dim3(S_ / 32, D_ / 32, B_ * KVH_), t32x8, 0, stream>>>(vraw, vtb);

    // causal GQA attention + gate
    flash_mfma<<<dim3(S_ / 64, B_ * H_), 256, 0, stream>>>(qro, kro, vtb, mixedq, attg);

    // output projection (fp32 out)
    gemm_bt<float><<<dim3(2048 / 128, M / 128), 256, 0, stream>>>(attg, Wot, out, M, 2048, 2048);
}

// Round 4
// 425.345 us; speedup vs baseline: 15.7268x; 1.2108x over previous
//
#include <hip/hip_runtime.h>
#include <hip/hip_bf16.h>

#define B_ 2
#define S_ 2048
#define HID_ 2048
#define H_ 16
#define KVH_ 8
#define D_ 128
#define G_ 2
#define EPS_ 1e-6f
#define SCALE_ 0.08838834764831845f
#define NQKV 6144

typedef __hip_bfloat16 bf16;
typedef __attribute__((ext_vector_type(8))) short s8v;   // 8 bf16 = 4 VGPR
typedef __attribute__((ext_vector_type(4))) float f4v;   // MFMA C/D

__device__ __forceinline__ unsigned short f2b(float f) {
    __hip_bfloat16 h = __float2bfloat16(f);
    return *reinterpret_cast<unsigned short*>(&h);
}
__device__ __forceinline__ float b2f(short u) {
    unsigned int x = ((unsigned int)(unsigned short)u) << 16;
    return __builtin_bit_cast(float, x);
}

__device__ __forceinline__ f4v MFMA(s8v a, s8v b, f4v c) {
    return __builtin_amdgcn_mfma_f32_16x16x32_bf16(a, b, c, 0, 0, 0);
}

__device__ __forceinline__ void gl_lds16(const void* g, void* l) {
    __builtin_amdgcn_global_load_lds(
        (const __attribute__((address_space(1))) void*)g,
        (__attribute__((address_space(3))) void*)l, 16, 0, 0);
}

__device__ __forceinline__ void cstore(float* p, float v) { *p = v; }
__device__ __forceinline__ void cstore(short* p, float v) { *p = (short)f2b(v); }

// ---------------------------------------------------------------------------
// fp32 -> bf16 bulk convert (vectorized)
// ---------------------------------------------------------------------------
__global__ __launch_bounds__(256) void f2bf_kernel(const float* __restrict__ in,
                                                   short* __restrict__ out, int n4) {
    int i = blockIdx.x * 256 + threadIdx.x;
    if (i >= n4) return;
    const float4 v = *(const float4*)(in + (size_t)i * 4);
    ushort4 o;
    o.x = f2b(v.x); o.y = f2b(v.y); o.z = f2b(v.z); o.w = f2b(v.w);
    *(ushort4*)(out + (size_t)i * 4) = o;
}

// ---------------------------------------------------------------------------
// W[K][N] fp32  ->  Wt[N][K] bf16   (32x32 LDS tile transpose)
// ---------------------------------------------------------------------------
__global__ __launch_bounds__(256) void transpose_conv(const float* __restrict__ in,
                                                      short* __restrict__ out,
                                                      int K, int N) {
    __shared__ short t[32][33];
    const int n0 = blockIdx.x * 32, k0 = blockIdx.y * 32;
    const int tx = threadIdx.x, ty = threadIdx.y;
#pragma unroll
    for (int j = 0; j < 4; j++) {
        const int r = ty + j * 8;
        t[r][tx] = (short)f2b(in[(size_t)(k0 + r) * N + n0 + tx]);
    }
    __syncthreads();
#pragma unroll
    for (int j = 0; j < 4; j++) {
        const int r = ty + j * 8;
        out[(size_t)(n0 + r) * K + k0 + tx] = t[tx][r];
    }
}

// ---------------------------------------------------------------------------
// V transpose per head: qkv v-columns -> vt[(b*KVH+kvh)][D][S]
// ---------------------------------------------------------------------------
__global__ __launch_bounds__(256) void transpose_v(const short* __restrict__ in,
                                                   short* __restrict__ out) {
    __shared__ short t[32][33];
    const int s0 = blockIdx.x * 32, d0 = blockIdx.y * 32, bk = blockIdx.z;
    const int b = bk / KVH_, kvh = bk % KVH_;
    const short* ip = in + (size_t)b * S_ * NQKV + kvh * D_;
    const int tx = threadIdx.x, ty = threadIdx.y;
#pragma unroll
    for (int j = 0; j < 4; j++) {
        const int r = ty + j * 8;
        t[r][tx] = ip[(size_t)(s0 + r) * NQKV + d0 + tx];
    }
    __syncthreads();
#pragma unroll
    for (int j = 0; j < 4; j++) {
        const int r = ty + j * 8;
        out[((size_t)bk * D_ + d0 + r) * S_ + s0 + tx] = t[tx][r];
    }
}

// ---------------------------------------------------------------------------
// MFMA GEMM (B^T form): C[M,N] = A[M,K] @ Bt[N,K]^T, bf16 in, fp32 acc.
// 128x128 tile, BK=32, 4 waves (2x2). 2-phase double-buffered staging,
// read-side XOR slot swizzle, bijective XCD blockid swizzle (needs nwg%8==0).
// GATED=1: A element (row,k) lives at row*NQKV + ((k>>7)<<8) + (k&127).
// ---------------------------------------------------------------------------
template <typename CT, int GATED>
__global__ __launch_bounds__(256) void gemm_bt(const short* __restrict__ A,
                                               const short* __restrict__ Bt,
                                               CT* __restrict__ C,
                                               int M, int N, int K) {
    __shared__ __align__(16) short As[2][128][32];
    __shared__ __align__(16) short Bs[2][128][32];
    const int tid = threadIdx.x;
    const int w = tid >> 6, l = tid & 63;
    const int lr = l & 15, g = l >> 4;
    const int nwg = gridDim.x * gridDim.y;
    int bid = blockIdx.y * gridDim.x + blockIdx.x;
    bid = (bid & 7) * (nwg >> 3) + (bid >> 3);
    const int bx = bid % gridDim.x, by = bid / gridDim.x;
    const int row0 = by * 128, col0 = bx * 128;
    const int wr = w >> 1, wc = w & 1;

    f4v acc[4][4];
#pragma unroll
    for (int i = 0; i < 4; i++)
#pragma unroll
        for (int j = 0; j < 4; j++) acc[i][j] = (f4v)0.f;

    const int srow = l >> 2;                       // row within 16-row chunk
    const int sg = (l & 3) ^ ((srow >> 1) & 3);    // swizzled source 16B chunk

    auto stage = [&](int buf, int kt) {
        const int k = kt + sg * 8;
#pragma unroll
        for (int i = 0; i < 2; i++) {
            const int rb = (w * 2 + i) * 16;
            size_t aoff;
            if constexpr (GATED)
                aoff = (size_t)(row0 + rb + srow) * NQKV + ((k >> 7) << 8) + (k & 127);
            else
                aoff = (size_t)(row0 + rb + srow) * K + k;
            gl_lds16(A + aoff, &As[buf][rb][0]);
            gl_lds16(Bt + (size_t)(col0 + rb + srow) * K + k, &Bs[buf][rb][0]);
        }
    };

    stage(0, 0);
    int cur = 0;
    const int rdslot = (g ^ ((lr >> 1) & 3)) * 8;  // same for all frags
    for (int kt = 0; kt < K; kt += 32) {
        __syncthreads();
        if (kt + 32 < K) stage(cur ^ 1, kt + 32);
        s8v a[4], b[4];
#pragma unroll
        for (int mi = 0; mi < 4; mi++)
            a[mi] = *(const s8v*)&As[cur][wr * 64 + mi * 16 + lr][rdslot];
#pragma unroll
        for (int ni = 0; ni < 4; ni++)
            b[ni] = *(const s8v*)&Bs[cur][wc * 64 + ni * 16 + lr][rdslot];
#pragma unroll
        for (int mi = 0; mi < 4; mi++)
#pragma unroll
            for (int ni = 0; ni < 4; ni++)
                acc[mi][ni] = MFMA(a[mi], b[ni], acc[mi][ni]);
        cur ^= 1;
    }

#pragma unroll
    for (int mi = 0; mi < 4; mi++)
#pragma unroll
        for (int ni = 0; ni < 4; ni++) {
            const int row = row0 + wr * 64 + mi * 16 + g * 4;
            const int col = col0 + wc * 64 + ni * 16 + lr;
#pragma unroll
            for (int j = 0; j < 4; j++)
                cstore(&C[(size_t)(row + j) * N + col], acc[mi][ni][j]);
        }
}

// ---------------------------------------------------------------------------
// Per-(b,s,head) RMSNorm + RoPE (src row-strided for merged qkv buffer).
// ---------------------------------------------------------------------------
__global__ __launch_bounds__(128) void norm_rope(const bf16* __restrict__ src,
                                                 const float* __restrict__ normw,
                                                 const float* __restrict__ cosb,
                                                 const float* __restrict__ sinb,
                                                 bf16* __restrict__ dst,
                                                 int NH, int rowStride, int chanStride) {
    const int idx = blockIdx.x;
    const int h = idx % NH;
    const int s = (idx / NH) % S_;
    const int b = idx / (NH * S_);
    const int d = threadIdx.x;

    const size_t src_i = (size_t)(b * S_ + s) * rowStride + h * chanStride + d;
    const size_t dst_i = (((size_t)b * NH + h) * S_ + s) * D_ + d;

    float x = __bfloat162float(src[src_i]);
    float sq = x * x;
#pragma unroll
    for (int o = 32; o > 0; o >>= 1) sq += __shfl_down(sq, o);
    __shared__ float red[2];
    __shared__ float sh[128];
    if ((d & 63) == 0) red[d >> 6] = sq;
    __syncthreads();
    const float var = (red[0] + red[1]) * (1.f / 128.f);
    const float xn = x * rsqrtf(var + EPS_) * normw[d];
    sh[d] = xn;
    __syncthreads();
    const float rot = (d < 64) ? -sh[d + 64] : sh[d - 64];
    const size_t cs_i = ((size_t)b * S_ + s) * D_ + d;
    dst[dst_i] = __float2bfloat16(xn * cosb[cs_i] + rot * sinb[cs_i]);
}

// ---------------------------------------------------------------------------
// MFMA causal GQA flash attention + sigmoid gate.
// grid = (S/64, B*H), 256 thr. 4 waves x 16 q-rows; KV tile = 64.
// 2-phase double-buffered KV staging, T13 defer-rescale, setprio MFMA.
// Gate read from qkv; output written into qkv's dead q-columns.
// ---------------------------------------------------------------------------
__global__ __launch_bounds__(256) void flash_mfma(const short* __restrict__ qro,
                                                  const short* __restrict__ kro,
                                                  const short* __restrict__ vt,
                                                  short* __restrict__ qkv) {
    __shared__ __align__(16) short Ks[2][64][128];   // [key][d], slot-swizzled
    __shared__ __align__(16) short Vs[2][128][64];   // [d][key], slot-swizzled
    __shared__ __align__(16) short Pl[4][16][84];    // per-wave P transpose

    const int tid = threadIdx.x;
    const int w = tid >> 6, l = tid & 63;
    const int lr = l & 15, g = l >> 4;
    const int qt = (int)gridDim.x - 1 - (int)blockIdx.x;  // heavy blocks first
    const int bh = blockIdx.y;
    const int b = bh >> 4, h = bh & 15;
    const int kvh = h >> 1;
    const int q0 = qt * 64;
    const int qw0 = q0 + w * 16;

    const short* qbase = qro + (size_t)(b * H_ + h) * S_ * D_;
    const short* kbase = kro + (size_t)(b * KVH_ + kvh) * S_ * D_;
    const short* vbase = vt + (size_t)(b * KVH_ + kvh) * D_ * S_;

    s8v qa[4];
#pragma unroll
    for (int kc = 0; kc < 4; kc++)
        qa[kc] = *(const s8v*)(qbase + (size_t)(qw0 + lr) * D_ + kc * 32 + g * 8);

    f4v oacc[8];
#pragma unroll
    for (int i = 0; i < 8; i++) oacc[i] = (f4v)0.f;
    float m[4] = {-3e38f, -3e38f, -3e38f, -3e38f};
    float lsum[4] = {0.f, 0.f, 0.f, 0.f};

    auto stage = [&](int buf, int kt) {
        const int kb0 = kt * 64;
#pragma unroll
        for (int i = 0; i < 4; i++) {
            const int li = w * 4 + i;
            {
                const int r = li * 4 + (l >> 4);
                const int sgk = (l & 15) ^ (r & 7);
                gl_lds16(kbase + (size_t)(kb0 + r) * D_ + sgk * 8, &Ks[buf][li * 4][0]);
            }
            {
                const int r = li * 8 + (l >> 3);
                const int sgv = (l & 7) ^ (r & 7);
                gl_lds16(vbase + (size_t)r * S_ + kb0 + sgv * 8, &Vs[buf][li * 8][0]);
            }
        }
    };

    const int nkt = qt + 1;
    stage(0, 0);
    int cur = 0;
    for (int kt = 0; kt < nkt; kt++) {
        __syncthreads();
        if (kt + 1 < nkt) stage(cur ^ 1, kt + 1);
        const int kb0 = kt * 64;

        // ---- QK^T: S[16 q][64 keys] ----
        f4v sacc[4];
#pragma unroll
        for (int ni = 0; ni < 4; ni++) sacc[ni] = (f4v)0.f;
        __builtin_amdgcn_s_setprio(1);
#pragma unroll
        for (int ni = 0; ni < 4; ni++) {
            const int r = ni * 16 + lr;
#pragma unroll
            for (int kc = 0; kc < 4; kc++) {
                const int ph = (kc * 4 + g) ^ (r & 7);
                const s8v kb = *(const s8v*)&Ks[cur][r][ph * 8];
                sacc[ni] = MFMA(qa[kc], kb, sacc[ni]);
            }
        }
        __builtin_amdgcn_s_setprio(0);

        // ---- online softmax with T13 defer-rescale ----
        const bool masked = (kt == qt);
        float p[4][4], tmax[4];
#pragma unroll
        for (int j = 0; j < 4; j++) {
            float v0 = -3e38f;
#pragma unroll
            for (int ni = 0; ni < 4; ni++) {
                float sc = sacc[ni][j] * SCALE_;
                if (masked && (kb0 + ni * 16 + lr > qw0 + g * 4 + j)) sc = -3e38f;
                p[ni][j] = sc;
                v0 = fmaxf(v0, sc);
            }
            tmax[j] = v0;
        }
#pragma unroll
        for (int off = 1; off < 16; off <<= 1)
#pragma unroll
            for (int j = 0; j < 4; j++)
                tmax[j] = fmaxf(tmax[j], __shfl_xor(tmax[j], off));

        bool needb = false;
#pragma unroll
        for (int j = 0; j < 4; j++) needb = needb || (tmax[j] > m[j] + 5.f);
        const bool doresc = __any((int)needb);

        float cj[4], psum[4];
#pragma unroll
        for (int j = 0; j < 4; j++) {
            float mn = m[j];
            if (doresc) {
                mn = fmaxf(m[j], tmax[j]);
                cj[j] = __expf(m[j] - mn);
                m[j] = mn;
            }
            float ps = 0.f;
#pragma unroll
            for (int ni = 0; ni < 4; ni++) {
                const float e = __expf(p[ni][j] - mn);
                p[ni][j] = e;
                ps += e;
            }
            psum[j] = ps;
        }
#pragma unroll
        for (int off = 1; off < 16; off <<= 1)
#pragma unroll
            for (int j = 0; j < 4; j++) psum[j] += __shfl_xor(psum[j], off);

        if (doresc) {
#pragma unroll
            for (int j = 0; j < 4; j++) lsum[j] = lsum[j] * cj[j] + psum[j];
#pragma unroll
            for (int di = 0; di < 8; di++)
#pragma unroll
                for (int j = 0; j < 4; j++) oacc[di][j] *= cj[j];
        } else {
#pragma unroll
            for (int j = 0; j < 4; j++) lsum[j] += psum[j];
        }

        // ---- P -> bf16 via LDS transpose (wave-private) ----
#pragma unroll
        for (int ni = 0; ni < 4; ni++)
#pragma unroll
            for (int j = 0; j < 4; j++)
                Pl[w][g * 4 + j][ni * 16 + lr] = (short)f2b(p[ni][j]);

        // ---- PV: O += P[16x64] @ V[64x128] ----
        __builtin_amdgcn_s_setprio(1);
#pragma unroll
        for (int kk = 0; kk < 2; kk++) {
            const s8v pa = *(const s8v*)&Pl[w][lr][kk * 32 + g * 8];
#pragma unroll
            for (int di = 0; di < 8; di++) {
                const int r = di * 16 + lr;
                const int ph = (kk * 4 + g) ^ (r & 7);
                const s8v vb = *(const s8v*)&Vs[cur][r][ph * 8];
                oacc[di] = MFMA(pa, vb, oacc[di]);
            }
        }
        __builtin_amdgcn_s_setprio(0);
        cur ^= 1;
    }

    // ---- epilogue: 1/l, sigmoid gate, store into qkv q-columns ----
    float linv[4];
#pragma unroll
    for (int j = 0; j < 4; j++) linv[j] = 1.f / lsum[j];
#pragma unroll
    for (int di = 0; di < 8; di++) {
        const int d = di * 16 + lr;
#pragma unroll
        for (int j = 0; j < 4; j++) {
            const int q = qw0 + g * 4 + j;
            const size_t base = (size_t)(b * S_ + q) * NQKV + h * 256;
            const float gate = b2f(qkv[base + 128 + d]);
            const float o = oacc[di][j] * linv[j] * (1.f / (1.f + __expf(-gate)));
            qkv[base + d] = (short)f2b(o);
        }
    }
}

// ---------------------------------------------------------------------------
extern "C" void kernel_launch(void* const* d_in, const int* in_sizes, int n_in,
                              void* d_out, int out_size, void* d_ws, size_t ws_size,
                              hipStream_t stream) {
    const float* hs = (const float*)d_in[0];
    const float* cosb = (const float*)d_in[1];
    const float* sinb = (const float*)d_in[2];
    const float* Wq = (const float*)d_in[3];
    const float* Wk = (const float*)d_in[4];
    const float* Wv = (const float*)d_in[5];
    const float* Wo = (const float*)d_in[6];
    const float* qnw = (const float*)d_in[7];
    const float* knw = (const float*)d_in[8];
    float* out = (float*)d_out;

    short* ws = (short*)d_ws;
    short* Wot = ws;                  // 4194304
    short* Wt  = ws + 4194304;        // 12582912 (Wq^T rows 0..4095, Wk^T 4096.., Wv^T 5120..)
    short* hsb = ws + 16777216;       // 8388608
    short* qkv = ws + 25165824;       // 25165824  (total = 50331648 shorts = 96 MiB)
    // reuse after QKV gemm:
    short* qro = Wt;                  // 8388608
    short* kro = Wt + 8388608;        // 4194304
    short* vtb = hsb;                 // 4194304

    const int M = B_ * S_;
    const dim3 t32x8(32, 8, 1);

    // bf16 conversions / transposes
    f2bf_kernel<<<8192, 256, 0, stream>>>(hs, hsb, 2097152);
    transpose_conv<<<dim3(128, 64), t32x8, 0, stream>>>(Wq, Wt, HID_, 4096);
    transpose_conv<<<dim3(32, 64), t32x8, 0, stream>>>(Wk, Wt + (size_t)4096 * 2048, HID_, 1024);
    transpose_conv<<<dim3(32, 64), t32x8, 0, stream>>>(Wv, Wt + (size_t)5120 * 2048, HID_, 1024);
    transpose_conv<<<dim3(64, 64), t32x8, 0, stream>>>(Wo, Wot, 2048, 2048);

    // merged QKV projection (bf16 MFMA): qkv[M][6144]
    gemm_bt<short, 0><<<dim3(48, 32), 256, 0, stream>>>(hsb, Wt, qkv, M, NQKV, HID_);

    // RMSNorm + RoPE
    norm_rope<<<dim3(B_ * S_ * H_), 128, 0, stream>>>((const bf16*)qkv, qnw, cosb, sinb,
                                                      (bf16*)qro, H_, NQKV, 256);
    norm_rope<<<dim3(B_ * S_ * KVH_), 128, 0, stream>>>((const bf16*)(qkv + 4096), knw, cosb, sinb,
                                                        (bf16*)kro, KVH_, NQKV, 128);

    // V transpose to [head][D][S]
    transpose_v<<<dim3(64, 4, 16), t32x8, 0, stream>>>(qkv + 5120, vtb);

    // causal GQA attention + gate (writes into qkv q-columns)
    flash_mfma<<<dim3(32, 32), 256, 0, stream>>>(qro, kro, vtb, qkv);

    // output projection (fp32 out), A read from qkv gated layout
    gemm_bt<float, 1><<<dim3(16, 32), 256, 0, stream>>>(qkv, Wot, out, M, HID_, 2048);
}

// Round 5
// 396.660 us; speedup vs baseline: 16.8641x; 1.0723x over previous
//
#include <hip/hip_runtime.h>
#include <hip/hip_bf16.h>

#define B_ 2
#define S_ 2048
#define HID_ 2048
#define H_ 16
#define KVH_ 8
#define D_ 128
#define G_ 2
#define EPS_ 1e-6f
#define SCALE_ 0.08838834764831845f
#define NQKV 6144

typedef __hip_bfloat16 bf16;
typedef __attribute__((ext_vector_type(8))) short s8v;   // 8 bf16 = 4 VGPR
typedef __attribute__((ext_vector_type(4))) float f4v;   // MFMA C/D

__device__ __forceinline__ unsigned short f2b(float f) {
    __hip_bfloat16 h = __float2bfloat16(f);
    return *reinterpret_cast<unsigned short*>(&h);
}
__device__ __forceinline__ float b2f(short u) {
    unsigned int x = ((unsigned int)(unsigned short)u) << 16;
    return __builtin_bit_cast(float, x);
}

__device__ __forceinline__ f4v MFMA(s8v a, s8v b, f4v c) {
    return __builtin_amdgcn_mfma_f32_16x16x32_bf16(a, b, c, 0, 0, 0);
}

__device__ __forceinline__ void gl_lds16(const void* g, void* l) {
    __builtin_amdgcn_global_load_lds(
        (const __attribute__((address_space(1))) void*)g,
        (__attribute__((address_space(3))) void*)l, 16, 0, 0);
}

__device__ __forceinline__ void cstore(float* p, float v) { *p = v; }
__device__ __forceinline__ void cstore(short* p, float v) { *p = (short)f2b(v); }

// ---- DPP 16-lane butterfly reduction (VALU, no LDS swizzle) ----
// 0xB1 = quad_perm[1,0,3,2] (xor1), 0x4E = quad_perm[2,3,0,1] (xor2),
// 0x124 = row_ror:4, 0x128 = row_ror:8 (row = 16 lanes on CDNA).
template <int CTRL>
__device__ __forceinline__ float dpp_f(float x) {
    return __builtin_bit_cast(float,
        __builtin_amdgcn_update_dpp(0, __builtin_bit_cast(int, x), CTRL, 0xF, 0xF, true));
}
__device__ __forceinline__ float red16_max(float v) {
    v = fmaxf(v, dpp_f<0xB1>(v));
    v = fmaxf(v, dpp_f<0x4E>(v));
    v = fmaxf(v, dpp_f<0x124>(v));
    v = fmaxf(v, dpp_f<0x128>(v));
    return v;
}
__device__ __forceinline__ float red16_sum(float v) {
    v += dpp_f<0xB1>(v);
    v += dpp_f<0x4E>(v);
    v += dpp_f<0x124>(v);
    v += dpp_f<0x128>(v);
    return v;
}

// ---------------------------------------------------------------------------
// fp32 -> bf16 bulk convert (vectorized)
// ---------------------------------------------------------------------------
__global__ __launch_bounds__(256) void f2bf_kernel(const float* __restrict__ in,
                                                   short* __restrict__ out, int n4) {
    int i = blockIdx.x * 256 + threadIdx.x;
    if (i >= n4) return;
    const float4 v = *(const float4*)(in + (size_t)i * 4);
    ushort4 o;
    o.x = f2b(v.x); o.y = f2b(v.y); o.z = f2b(v.z); o.w = f2b(v.w);
    *(ushort4*)(out + (size_t)i * 4) = o;
}

// ---------------------------------------------------------------------------
// W[K][N] fp32  ->  Wt[N][K] bf16   (32x32 LDS tile transpose)
// ---------------------------------------------------------------------------
__global__ __launch_bounds__(256) void transpose_conv(const float* __restrict__ in,
                                                      short* __restrict__ out,
                                                      int K, int N) {
    __shared__ short t[32][33];
    const int n0 = blockIdx.x * 32, k0 = blockIdx.y * 32;
    const int tx = threadIdx.x, ty = threadIdx.y;
#pragma unroll
    for (int j = 0; j < 4; j++) {
        const int r = ty + j * 8;
        t[r][tx] = (short)f2b(in[(size_t)(k0 + r) * N + n0 + tx]);
    }
    __syncthreads();
#pragma unroll
    for (int j = 0; j < 4; j++) {
        const int r = ty + j * 8;
        out[(size_t)(n0 + r) * K + k0 + tx] = t[tx][r];
    }
}

// ---------------------------------------------------------------------------
// V transpose per head: qkv v-columns -> vt[(b*KVH+kvh)][D][S]
// ---------------------------------------------------------------------------
__global__ __launch_bounds__(256) void transpose_v(const short* __restrict__ in,
                                                   short* __restrict__ out) {
    __shared__ short t[32][33];
    const int s0 = blockIdx.x * 32, d0 = blockIdx.y * 32, bk = blockIdx.z;
    const int b = bk / KVH_, kvh = bk % KVH_;
    const short* ip = in + (size_t)b * S_ * NQKV + kvh * D_;
    const int tx = threadIdx.x, ty = threadIdx.y;
#pragma unroll
    for (int j = 0; j < 4; j++) {
        const int r = ty + j * 8;
        t[r][tx] = ip[(size_t)(s0 + r) * NQKV + d0 + tx];
    }
    __syncthreads();
#pragma unroll
    for (int j = 0; j < 4; j++) {
        const int r = ty + j * 8;
        out[((size_t)bk * D_ + d0 + r) * S_ + s0 + tx] = t[tx][r];
    }
}

// ---------------------------------------------------------------------------
// MFMA GEMM (B^T form): C[M,N] = A[M,K] @ Bt[N,K]^T, bf16 in, fp32 acc.
// 128x128 tile, BK=32, 4 waves (2x2). 2-phase double-buffered staging,
// read-side XOR slot swizzle, bijective XCD blockid swizzle (needs nwg%8==0).
// GATED=1: A element (row,k) lives at row*NQKV + ((k>>7)<<8) + (k&127).
// ---------------------------------------------------------------------------
template <typename CT, int GATED>
__global__ __launch_bounds__(256) void gemm_bt(const short* __restrict__ A,
                                               const short* __restrict__ Bt,
                                               CT* __restrict__ C,
                                               int M, int N, int K) {
    __shared__ __align__(16) short As[2][128][32];
    __shared__ __align__(16) short Bs[2][128][32];
    const int tid = threadIdx.x;
    const int w = tid >> 6, l = tid & 63;
    const int lr = l & 15, g = l >> 4;
    const int nwg = gridDim.x * gridDim.y;
    int bid = blockIdx.y * gridDim.x + blockIdx.x;
    bid = (bid & 7) * (nwg >> 3) + (bid >> 3);
    const int bx = bid % gridDim.x, by = bid / gridDim.x;
    const int row0 = by * 128, col0 = bx * 128;
    const int wr = w >> 1, wc = w & 1;

    f4v acc[4][4];
#pragma unroll
    for (int i = 0; i < 4; i++)
#pragma unroll
        for (int j = 0; j < 4; j++) acc[i][j] = (f4v)0.f;

    const int srow = l >> 2;                       // row within 16-row chunk
    const int sg = (l & 3) ^ ((srow >> 1) & 3);    // swizzled source 16B chunk

    auto stage = [&](int buf, int kt) {
        const int k = kt + sg * 8;
#pragma unroll
        for (int i = 0; i < 2; i++) {
            const int rb = (w * 2 + i) * 16;
            size_t aoff;
            if constexpr (GATED)
                aoff = (size_t)(row0 + rb + srow) * NQKV + ((k >> 7) << 8) + (k & 127);
            else
                aoff = (size_t)(row0 + rb + srow) * K + k;
            gl_lds16(A + aoff, &As[buf][rb][0]);
            gl_lds16(Bt + (size_t)(col0 + rb + srow) * K + k, &Bs[buf][rb][0]);
        }
    };

    stage(0, 0);
    int cur = 0;
    const int rdslot = (g ^ ((lr >> 1) & 3)) * 8;  // same for all frags
    for (int kt = 0; kt < K; kt += 32) {
        __syncthreads();
        if (kt + 32 < K) stage(cur ^ 1, kt + 32);
        s8v a[4], b[4];
#pragma unroll
        for (int mi = 0; mi < 4; mi++)
            a[mi] = *(const s8v*)&As[cur][wr * 64 + mi * 16 + lr][rdslot];
#pragma unroll
        for (int ni = 0; ni < 4; ni++)
            b[ni] = *(const s8v*)&Bs[cur][wc * 64 + ni * 16 + lr][rdslot];
#pragma unroll
        for (int mi = 0; mi < 4; mi++)
#pragma unroll
            for (int ni = 0; ni < 4; ni++)
                acc[mi][ni] = MFMA(a[mi], b[ni], acc[mi][ni]);
        cur ^= 1;
    }

#pragma unroll
    for (int mi = 0; mi < 4; mi++)
#pragma unroll
        for (int ni = 0; ni < 4; ni++) {
            const int row = row0 + wr * 64 + mi * 16 + g * 4;
            const int col = col0 + wc * 64 + ni * 16 + lr;
#pragma unroll
            for (int j = 0; j < 4; j++)
                cstore(&C[(size_t)(row + j) * N + col], acc[mi][ni][j]);
        }
}

// ---------------------------------------------------------------------------
// Per-(b,s,head) RMSNorm + RoPE (src row-strided for merged qkv buffer).
// ---------------------------------------------------------------------------
__global__ __launch_bounds__(128) void norm_rope(const bf16* __restrict__ src,
                                                 const float* __restrict__ normw,
                                                 const float* __restrict__ cosb,
                                                 const float* __restrict__ sinb,
                                                 bf16* __restrict__ dst,
                                                 int NH, int rowStride, int chanStride) {
    const int idx = blockIdx.x;
    const int h = idx % NH;
    const int s = (idx / NH) % S_;
    const int b = idx / (NH * S_);
    const int d = threadIdx.x;

    const size_t src_i = (size_t)(b * S_ + s) * rowStride + h * chanStride + d;
    const size_t dst_i = (((size_t)b * NH + h) * S_ + s) * D_ + d;

    float x = __bfloat162float(src[src_i]);
    float sq = x * x;
#pragma unroll
    for (int o = 32; o > 0; o >>= 1) sq += __shfl_down(sq, o);
    __shared__ float red[2];
    __shared__ float sh[128];
    if ((d & 63) == 0) red[d >> 6] = sq;
    __syncthreads();
    const float var = (red[0] + red[1]) * (1.f / 128.f);
    const float xn = x * rsqrtf(var + EPS_) * normw[d];
    sh[d] = xn;
    __syncthreads();
    const float rot = (d < 64) ? -sh[d + 64] : sh[d - 64];
    const size_t cs_i = ((size_t)b * S_ + s) * D_ + d;
    dst[dst_i] = __float2bfloat16(xn * cosb[cs_i] + rot * sinb[cs_i]);
}

// ---------------------------------------------------------------------------
// MFMA causal GQA flash attention + sigmoid gate.
// grid = (S/64, B*H), 256 thr. 4 waves x 16 q-rows; KV tile = 64.
// 2-phase double-buffered KV staging, T13 defer-rescale, setprio MFMA,
// DPP butterfly softmax reductions (no ds_swizzle chains).
// Gate read from qkv; output written into qkv's dead q-columns.
// ---------------------------------------------------------------------------
__global__ __launch_bounds__(256) void flash_mfma(const short* __restrict__ qro,
                                                  const short* __restrict__ kro,
                                                  const short* __restrict__ vt,
                                                  short* __restrict__ qkv) {
    __shared__ __align__(16) short Ks[2][64][128];   // [key][d], slot-swizzled
    __shared__ __align__(16) short Vs[2][128][64];   // [d][key], slot-swizzled
    __shared__ __align__(16) short Pl[4][16][84];    // per-wave P transpose

    const int tid = threadIdx.x;
    const int w = tid >> 6, l = tid & 63;
    const int lr = l & 15, g = l >> 4;
    const int qt = (int)gridDim.x - 1 - (int)blockIdx.x;  // heavy blocks first
    const int bh = blockIdx.y;
    const int b = bh >> 4, h = bh & 15;
    const int kvh = h >> 1;
    const int q0 = qt * 64;
    const int qw0 = q0 + w * 16;

    const short* qbase = qro + (size_t)(b * H_ + h) * S_ * D_;
    const short* kbase = kro + (size_t)(b * KVH_ + kvh) * S_ * D_;
    const short* vbase = vt + (size_t)(b * KVH_ + kvh) * D_ * S_;

    s8v qa[4];
#pragma unroll
    for (int kc = 0; kc < 4; kc++)
        qa[kc] = *(const s8v*)(qbase + (size_t)(qw0 + lr) * D_ + kc * 32 + g * 8);

    f4v oacc[8];
#pragma unroll
    for (int i = 0; i < 8; i++) oacc[i] = (f4v)0.f;
    float m[4] = {-3e38f, -3e38f, -3e38f, -3e38f};
    float lsum[4] = {0.f, 0.f, 0.f, 0.f};

    auto stage = [&](int buf, int kt) {
        const int kb0 = kt * 64;
#pragma unroll
        for (int i = 0; i < 4; i++) {
            const int li = w * 4 + i;
            {
                const int r = li * 4 + (l >> 4);
                const int sgk = (l & 15) ^ (r & 7);
                gl_lds16(kbase + (size_t)(kb0 + r) * D_ + sgk * 8, &Ks[buf][li * 4][0]);
            }
            {
                const int r = li * 8 + (l >> 3);
                const int sgv = (l & 7) ^ (r & 7);
                gl_lds16(vbase + (size_t)r * S_ + kb0 + sgv * 8, &Vs[buf][li * 8][0]);
            }
        }
    };

    const int nkt = qt + 1;
    stage(0, 0);
    int cur = 0;
    for (int kt = 0; kt < nkt; kt++) {
        __syncthreads();
        if (kt + 1 < nkt) stage(cur ^ 1, kt + 1);
        const int kb0 = kt * 64;

        // ---- QK^T: S[16 q][64 keys] ----
        f4v sacc[4];
#pragma unroll
        for (int ni = 0; ni < 4; ni++) sacc[ni] = (f4v)0.f;
        __builtin_amdgcn_s_setprio(1);
#pragma unroll
        for (int ni = 0; ni < 4; ni++) {
            const int r = ni * 16 + lr;
#pragma unroll
            for (int kc = 0; kc < 4; kc++) {
                const int ph = (kc * 4 + g) ^ (r & 7);
                const s8v kb = *(const s8v*)&Ks[cur][r][ph * 8];
                sacc[ni] = MFMA(qa[kc], kb, sacc[ni]);
            }
        }
        __builtin_amdgcn_s_setprio(0);

        // ---- online softmax with T13 defer-rescale; DPP reductions ----
        const bool masked = (kt == qt);
        float p[4][4], tmax[4];
#pragma unroll
        for (int j = 0; j < 4; j++) {
            float v0 = -3e38f;
#pragma unroll
            for (int ni = 0; ni < 4; ni++) {
                float sc = sacc[ni][j] * SCALE_;
                if (masked && (kb0 + ni * 16 + lr > qw0 + g * 4 + j)) sc = -3e38f;
                p[ni][j] = sc;
                v0 = fmaxf(v0, sc);
            }
            tmax[j] = v0;
        }
#pragma unroll
        for (int j = 0; j < 4; j++) tmax[j] = red16_max(tmax[j]);

        bool needb = false;
#pragma unroll
        for (int j = 0; j < 4; j++) needb = needb || (tmax[j] > m[j] + 5.f);
        const bool doresc = __any((int)needb);

        float cj[4], psum[4];
#pragma unroll
        for (int j = 0; j < 4; j++) {
            float mn = m[j];
            if (doresc) {
                mn = fmaxf(m[j], tmax[j]);
                cj[j] = __expf(m[j] - mn);
                m[j] = mn;
            }
            float ps = 0.f;
#pragma unroll
            for (int ni = 0; ni < 4; ni++) {
                const float e = __expf(p[ni][j] - mn);
                p[ni][j] = e;
                ps += e;
            }
            psum[j] = ps;
        }

        // ---- P -> bf16 via LDS transpose (overlaps the DPP sum below) ----
#pragma unroll
        for (int ni = 0; ni < 4; ni++)
#pragma unroll
            for (int j = 0; j < 4; j++)
                Pl[w][g * 4 + j][ni * 16 + lr] = (short)f2b(p[ni][j]);

#pragma unroll
        for (int j = 0; j < 4; j++) psum[j] = red16_sum(psum[j]);

        if (doresc) {
#pragma unroll
            for (int j = 0; j < 4; j++) lsum[j] = lsum[j] * cj[j] + psum[j];
#pragma unroll
            for (int di = 0; di < 8; di++)
#pragma unroll
                for (int j = 0; j < 4; j++) oacc[di][j] *= cj[j];
        } else {
#pragma unroll
            for (int j = 0; j < 4; j++) lsum[j] += psum[j];
        }

        // ---- PV: O += P[16x64] @ V[64x128] ----
        __builtin_amdgcn_s_setprio(1);
#pragma unroll
        for (int kk = 0; kk < 2; kk++) {
            const s8v pa = *(const s8v*)&Pl[w][lr][kk * 32 + g * 8];
#pragma unroll
            for (int di = 0; di < 8; di++) {
                const int r = di * 16 + lr;
                const int ph = (kk * 4 + g) ^ (r & 7);
                const s8v vb = *(const s8v*)&Vs[cur][r][ph * 8];
                oacc[di] = MFMA(pa, vb, oacc[di]);
            }
        }
        __builtin_amdgcn_s_setprio(0);
        cur ^= 1;
    }

    // ---- epilogue: 1/l, sigmoid gate, store into qkv q-columns ----
    float linv[4];
#pragma unroll
    for (int j = 0; j < 4; j++) linv[j] = 1.f / lsum[j];
#pragma unroll
    for (int di = 0; di < 8; di++) {
        const int d = di * 16 + lr;
#pragma unroll
        for (int j = 0; j < 4; j++) {
            const int q = qw0 + g * 4 + j;
            const size_t base = (size_t)(b * S_ + q) * NQKV + h * 256;
            const float gate = b2f(qkv[base + 128 + d]);
            const float o = oacc[di][j] * linv[j] * (1.f / (1.f + __expf(-gate)));
            qkv[base + d] = (short)f2b(o);
        }
    }
}

// ---------------------------------------------------------------------------
extern "C" void kernel_launch(void* const* d_in, const int* in_sizes, int n_in,
                              void* d_out, int out_size, void* d_ws, size_t ws_size,
                              hipStream_t stream) {
    const float* hs = (const float*)d_in[0];
    const float* cosb = (const float*)d_in[1];
    const float* sinb = (const float*)d_in[2];
    const float* Wq = (const float*)d_in[3];
    const float* Wk = (const float*)d_in[4];
    const float* Wv = (const float*)d_in[5];
    const float* Wo = (const float*)d_in[6];
    const float* qnw = (const float*)d_in[7];
    const float* knw = (const float*)d_in[8];
    float* out = (float*)d_out;

    short* ws = (short*)d_ws;
    short* Wot = ws;                  // 4194304
    short* Wt  = ws + 4194304;        // 12582912 (Wq^T rows 0..4095, Wk^T 4096.., Wv^T 5120..)
    short* hsb = ws + 16777216;       // 8388608
    short* qkv = ws + 25165824;       // 25165824  (total = 50331648 shorts = 96 MiB)
    // reuse after QKV gemm:
    short* qro = Wt;                  // 8388608
    short* kro = Wt + 8388608;        // 4194304
    short* vtb = hsb;                 // 4194304

    const int M = B_ * S_;
    const dim3 t32x8(32, 8, 1);

    // bf16 conversions / transposes
    f2bf_kernel<<<8192, 256, 0, stream>>>(hs, hsb, 2097152);
    transpose_conv<<<dim3(128, 64), t32x8, 0, stream>>>(Wq, Wt, HID_, 4096);
    transpose_conv<<<dim3(32, 64), t32x8, 0, stream>>>(Wk, Wt + (size_t)4096 * 2048, HID_, 1024);
    transpose_conv<<<dim3(32, 64), t32x8, 0, stream>>>(Wv, Wt + (size_t)5120 * 2048, HID_, 1024);
    transpose_conv<<<dim3(64, 64), t32x8, 0, stream>>>(Wo, Wot, 2048, 2048);

    // merged QKV projection (bf16 MFMA): qkv[M][6144]
    gemm_bt<short, 0><<<dim3(48, 32), 256, 0, stream>>>(hsb, Wt, qkv, M, NQKV, HID_);

    // RMSNorm + RoPE
    norm_rope<<<dim3(B_ * S_ * H_), 128, 0, stream>>>((const bf16*)qkv, qnw, cosb, sinb,
                                                      (bf16*)qro, H_, NQKV, 256);
    norm_rope<<<dim3(B_ * S_ * KVH_), 128, 0, stream>>>((const bf16*)(qkv + 4096), knw, cosb, sinb,
                                                        (bf16*)kro, KVH_, NQKV, 128);

    // V transpose to [head][D][S]
    transpose_v<<<dim3(64, 4, 16), t32x8, 0, stream>>>(qkv + 5120, vtb);

    // causal GQA attention + gate (writes into qkv q-columns)
    flash_mfma<<<dim3(32, 32), 256, 0, stream>>>(qro, kro, vtb, qkv);

    // output projection (fp32 out), A read from qkv gated layout
    gemm_bt<float, 1><<<dim3(16, 32), 256, 0, stream>>>(qkv, Wot, out, M, HID_, 2048);
}

// Round 6
// 333.543 us; speedup vs baseline: 20.0554x; 1.1892x over previous
//
#include <hip/hip_runtime.h>
#include <hip/hip_bf16.h>

#define B_ 2
#define S_ 2048
#define HID_ 2048
#define H_ 16
#define KVH_ 8
#define D_ 128
#define G_ 2
#define EPS_ 1e-6f
#define SCALE_ 0.08838834764831845f
// SCALE * log2(e): scores computed directly in log2 domain
#define SCALE2_ 0.1275313760443445f
#define NQKV 6144

typedef __hip_bfloat16 bf16;
typedef __attribute__((ext_vector_type(8))) short s8v;   // 8 bf16 = 4 VGPR
typedef __attribute__((ext_vector_type(4))) float f4v;   // MFMA C/D

__device__ __forceinline__ unsigned short f2b(float f) {
    __hip_bfloat16 h = __float2bfloat16(f);
    return *reinterpret_cast<unsigned short*>(&h);
}
__device__ __forceinline__ float b2f(short u) {
    unsigned int x = ((unsigned int)(unsigned short)u) << 16;
    return __builtin_bit_cast(float, x);
}

__device__ __forceinline__ f4v MFMA(s8v a, s8v b, f4v c) {
    return __builtin_amdgcn_mfma_f32_16x16x32_bf16(a, b, c, 0, 0, 0);
}

__device__ __forceinline__ void gl_lds16(const void* g, void* l) {
    __builtin_amdgcn_global_load_lds(
        (const __attribute__((address_space(1))) void*)g,
        (__attribute__((address_space(3))) void*)l, 16, 0, 0);
}

__device__ __forceinline__ void cstore(float* p, float v) { *p = v; }
__device__ __forceinline__ void cstore(short* p, float v) { *p = (short)f2b(v); }

// ---- DPP 16-lane butterfly reduction (VALU, no LDS swizzle) ----
template <int CTRL>
__device__ __forceinline__ float dpp_f(float x) {
    return __builtin_bit_cast(float,
        __builtin_amdgcn_update_dpp(0, __builtin_bit_cast(int, x), CTRL, 0xF, 0xF, true));
}
__device__ __forceinline__ float red16_max(float v) {
    v = fmaxf(v, dpp_f<0xB1>(v));
    v = fmaxf(v, dpp_f<0x4E>(v));
    v = fmaxf(v, dpp_f<0x124>(v));
    v = fmaxf(v, dpp_f<0x128>(v));
    return v;
}
__device__ __forceinline__ float red16_sum(float v) {
    v += dpp_f<0xB1>(v);
    v += dpp_f<0x4E>(v);
    v += dpp_f<0x124>(v);
    v += dpp_f<0x128>(v);
    return v;
}

// ---------------------------------------------------------------------------
// fp32 -> bf16 bulk convert (vectorized)
// ---------------------------------------------------------------------------
__global__ __launch_bounds__(256) void f2bf_kernel(const float* __restrict__ in,
                                                   short* __restrict__ out, int n4) {
    int i = blockIdx.x * 256 + threadIdx.x;
    if (i >= n4) return;
    const float4 v = *(const float4*)(in + (size_t)i * 4);
    ushort4 o;
    o.x = f2b(v.x); o.y = f2b(v.y); o.z = f2b(v.z); o.w = f2b(v.w);
    *(ushort4*)(out + (size_t)i * 4) = o;
}

// ---------------------------------------------------------------------------
// W[K][N] fp32  ->  Wt[N][K] bf16   (32x32 LDS tile transpose)
// ---------------------------------------------------------------------------
__global__ __launch_bounds__(256) void transpose_conv(const float* __restrict__ in,
                                                      short* __restrict__ out,
                                                      int K, int N) {
    __shared__ short t[32][33];
    const int n0 = blockIdx.x * 32, k0 = blockIdx.y * 32;
    const int tx = threadIdx.x, ty = threadIdx.y;
#pragma unroll
    for (int j = 0; j < 4; j++) {
        const int r = ty + j * 8;
        t[r][tx] = (short)f2b(in[(size_t)(k0 + r) * N + n0 + tx]);
    }
    __syncthreads();
#pragma unroll
    for (int j = 0; j < 4; j++) {
        const int r = ty + j * 8;
        out[(size_t)(n0 + r) * K + k0 + tx] = t[tx][r];
    }
}

// ---------------------------------------------------------------------------
// V transpose per head: qkv v-columns -> vt[(b*KVH+kvh)][D][S]
// ---------------------------------------------------------------------------
__global__ __launch_bounds__(256) void transpose_v(const short* __restrict__ in,
                                                   short* __restrict__ out) {
    __shared__ short t[32][33];
    const int s0 = blockIdx.x * 32, d0 = blockIdx.y * 32, bk = blockIdx.z;
    const int b = bk / KVH_, kvh = bk % KVH_;
    const short* ip = in + (size_t)b * S_ * NQKV + kvh * D_;
    const int tx = threadIdx.x, ty = threadIdx.y;
#pragma unroll
    for (int j = 0; j < 4; j++) {
        const int r = ty + j * 8;
        t[r][tx] = ip[(size_t)(s0 + r) * NQKV + d0 + tx];
    }
    __syncthreads();
#pragma unroll
    for (int j = 0; j < 4; j++) {
        const int r = ty + j * 8;
        out[((size_t)bk * D_ + d0 + r) * S_ + s0 + tx] = t[tx][r];
    }
}

// ---------------------------------------------------------------------------
// MFMA GEMM (B^T form): C[M,N] = A[M,K] @ Bt[N,K]^T, bf16 in, fp32 acc.
// 128x128 tile, BK=32, 4 waves (2x2). 2-phase double-buffered staging,
// read-side XOR slot swizzle, bijective XCD blockid swizzle (needs nwg%8==0).
// GATED=1: A element (row,k) lives at row*NQKV + ((k>>7)<<8) + (k&127).
// ---------------------------------------------------------------------------
template <typename CT, int GATED>
__global__ __launch_bounds__(256) void gemm_bt(const short* __restrict__ A,
                                               const short* __restrict__ Bt,
                                               CT* __restrict__ C,
                                               int M, int N, int K) {
    __shared__ __align__(16) short As[2][128][32];
    __shared__ __align__(16) short Bs[2][128][32];
    const int tid = threadIdx.x;
    const int w = tid >> 6, l = tid & 63;
    const int lr = l & 15, g = l >> 4;
    const int nwg = gridDim.x * gridDim.y;
    int bid = blockIdx.y * gridDim.x + blockIdx.x;
    bid = (bid & 7) * (nwg >> 3) + (bid >> 3);
    const int bx = bid % gridDim.x, by = bid / gridDim.x;
    const int row0 = by * 128, col0 = bx * 128;
    const int wr = w >> 1, wc = w & 1;

    f4v acc[4][4];
#pragma unroll
    for (int i = 0; i < 4; i++)
#pragma unroll
        for (int j = 0; j < 4; j++) acc[i][j] = (f4v)0.f;

    const int srow = l >> 2;                       // row within 16-row chunk
    const int sg = (l & 3) ^ ((srow >> 1) & 3);    // swizzled source 16B chunk

    auto stage = [&](int buf, int kt) {
        const int k = kt + sg * 8;
#pragma unroll
        for (int i = 0; i < 2; i++) {
            const int rb = (w * 2 + i) * 16;
            size_t aoff;
            if constexpr (GATED)
                aoff = (size_t)(row0 + rb + srow) * NQKV + ((k >> 7) << 8) + (k & 127);
            else
                aoff = (size_t)(row0 + rb + srow) * K + k;
            gl_lds16(A + aoff, &As[buf][rb][0]);
            gl_lds16(Bt + (size_t)(col0 + rb + srow) * K + k, &Bs[buf][rb][0]);
        }
    };

    stage(0, 0);
    int cur = 0;
    const int rdslot = (g ^ ((lr >> 1) & 3)) * 8;  // same for all frags
    for (int kt = 0; kt < K; kt += 32) {
        __syncthreads();
        if (kt + 32 < K) stage(cur ^ 1, kt + 32);
        s8v a[4], b[4];
#pragma unroll
        for (int mi = 0; mi < 4; mi++)
            a[mi] = *(const s8v*)&As[cur][wr * 64 + mi * 16 + lr][rdslot];
#pragma unroll
        for (int ni = 0; ni < 4; ni++)
            b[ni] = *(const s8v*)&Bs[cur][wc * 64 + ni * 16 + lr][rdslot];
#pragma unroll
        for (int mi = 0; mi < 4; mi++)
#pragma unroll
            for (int ni = 0; ni < 4; ni++)
                acc[mi][ni] = MFMA(a[mi], b[ni], acc[mi][ni]);
        cur ^= 1;
    }

#pragma unroll
    for (int mi = 0; mi < 4; mi++)
#pragma unroll
        for (int ni = 0; ni < 4; ni++) {
            const int row = row0 + wr * 64 + mi * 16 + g * 4;
            const int col = col0 + wc * 64 + ni * 16 + lr;
#pragma unroll
            for (int j = 0; j < 4; j++)
                cstore(&C[(size_t)(row + j) * N + col], acc[mi][ni][j]);
        }
}

// ---------------------------------------------------------------------------
// Per-(b,s,head) RMSNorm + RoPE (src row-strided for merged qkv buffer).
// ---------------------------------------------------------------------------
__global__ __launch_bounds__(128) void norm_rope(const bf16* __restrict__ src,
                                                 const float* __restrict__ normw,
                                                 const float* __restrict__ cosb,
                                                 const float* __restrict__ sinb,
                                                 bf16* __restrict__ dst,
                                                 int NH, int rowStride, int chanStride) {
    const int idx = blockIdx.x;
    const int h = idx % NH;
    const int s = (idx / NH) % S_;
    const int b = idx / (NH * S_);
    const int d = threadIdx.x;

    const size_t src_i = (size_t)(b * S_ + s) * rowStride + h * chanStride + d;
    const size_t dst_i = (((size_t)b * NH + h) * S_ + s) * D_ + d;

    float x = __bfloat162float(src[src_i]);
    float sq = x * x;
#pragma unroll
    for (int o = 32; o > 0; o >>= 1) sq += __shfl_down(sq, o);
    __shared__ float red[2];
    __shared__ float sh[128];
    if ((d & 63) == 0) red[d >> 6] = sq;
    __syncthreads();
    const float var = (red[0] + red[1]) * (1.f / 128.f);
    const float xn = x * rsqrtf(var + EPS_) * normw[d];
    sh[d] = xn;
    __syncthreads();
    const float rot = (d < 64) ? -sh[d + 64] : sh[d - 64];
    const size_t cs_i = ((size_t)b * S_ + s) * D_ + d;
    dst[dst_i] = __float2bfloat16(xn * cosb[cs_i] + rot * sinb[cs_i]);
}

// ---------------------------------------------------------------------------
// MFMA causal GQA flash attention + sigmoid gate.
// grid = (16, B*H), 256 thr. Each block processes TWO q-tiles {31-bx, bx}
// (33 KV-tile-iters each -> perfectly uniform load). 4 waves x 16 q-rows;
// KV tile = 64; 2-phase dbuf KV staging; DPP softmax in log2 domain with
// T13 defer-rescale; setprio around MFMA clusters.
// Gate read from qkv; output written into qkv's dead q-columns.
// ---------------------------------------------------------------------------
__global__ __launch_bounds__(256) void flash_mfma(const short* __restrict__ qro,
                                                  const short* __restrict__ kro,
                                                  const short* __restrict__ vt,
                                                  short* __restrict__ qkv) {
    __shared__ __align__(16) short Ks[2][64][128];   // [key][d], slot-swizzled
    __shared__ __align__(16) short Vs[2][128][64];   // [d][key], slot-swizzled
    __shared__ __align__(16) short Pl[4][16][84];    // per-wave P transpose

    const int tid = threadIdx.x;
    const int w = tid >> 6, l = tid & 63;
    const int lr = l & 15, g = l >> 4;
    const int bx = blockIdx.x;                       // 0..15
    const int bh = blockIdx.y;
    const int b = bh >> 4, h = bh & 15;
    const int kvh = h >> 1;

    const short* qbase = qro + (size_t)(b * H_ + h) * S_ * D_;
    const short* kbase = kro + (size_t)(b * KVH_ + kvh) * S_ * D_;
    const short* vbase = vt + (size_t)(b * KVH_ + kvh) * D_ * S_;

    auto stage = [&](int buf, int kt) {
        const int kb0 = kt * 64;
#pragma unroll
        for (int i = 0; i < 4; i++) {
            const int li = w * 4 + i;
            {
                const int r = li * 4 + (l >> 4);
                const int sgk = (l & 15) ^ (r & 7);
                gl_lds16(kbase + (size_t)(kb0 + r) * D_ + sgk * 8, &Ks[buf][li * 4][0]);
            }
            {
                const int r = li * 8 + (l >> 3);
                const int sgv = (l & 7) ^ (r & 7);
                gl_lds16(vbase + (size_t)r * S_ + kb0 + sgv * 8, &Vs[buf][li * 8][0]);
            }
        }
    };

#pragma unroll 1
    for (int seg = 0; seg < 2; seg++) {
        const int qt = seg ? bx : (31 - bx);         // heavy tile first
        const int q0 = qt * 64;
        const int qw0 = q0 + w * 16;

        if (seg) __syncthreads();                    // protect LDS reuse

        s8v qa[4];
#pragma unroll
        for (int kc = 0; kc < 4; kc++)
            qa[kc] = *(const s8v*)(qbase + (size_t)(qw0 + lr) * D_ + kc * 32 + g * 8);

        f4v oacc[8];
#pragma unroll
        for (int i = 0; i < 8; i++) oacc[i] = (f4v)0.f;
        float m[4] = {-3e38f, -3e38f, -3e38f, -3e38f};
        float lsum[4] = {0.f, 0.f, 0.f, 0.f};

        const int nkt = qt + 1;
        stage(0, 0);
        int cur = 0;
        for (int kt = 0; kt < nkt; kt++) {
            __syncthreads();
            if (kt + 1 < nkt) stage(cur ^ 1, kt + 1);
            const int kb0 = kt * 64;

            // ---- QK^T: S[16 q][64 keys] (log2 domain) ----
            f4v sacc[4];
#pragma unroll
            for (int ni = 0; ni < 4; ni++) sacc[ni] = (f4v)0.f;
            __builtin_amdgcn_s_setprio(1);
#pragma unroll
            for (int ni = 0; ni < 4; ni++) {
                const int r = ni * 16 + lr;
#pragma unroll
                for (int kc = 0; kc < 4; kc++) {
                    const int ph = (kc * 4 + g) ^ (r & 7);
                    const s8v kb = *(const s8v*)&Ks[cur][r][ph * 8];
                    sacc[ni] = MFMA(qa[kc], kb, sacc[ni]);
                }
            }
            __builtin_amdgcn_s_setprio(0);

            // ---- online softmax (log2), DPP reductions, defer-rescale ----
            const bool masked = (kt == qt);
            float p[4][4], tmax[4];
#pragma unroll
            for (int j = 0; j < 4; j++) {
                float v0 = -3e38f;
#pragma unroll
                for (int ni = 0; ni < 4; ni++) {
                    float sc = sacc[ni][j] * SCALE2_;
                    if (masked && (kb0 + ni * 16 + lr > qw0 + g * 4 + j)) sc = -3e38f;
                    p[ni][j] = sc;
                    v0 = fmaxf(v0, sc);
                }
                tmax[j] = v0;
            }
#pragma unroll
            for (int j = 0; j < 4; j++) tmax[j] = red16_max(tmax[j]);

            bool needb = false;
#pragma unroll
            for (int j = 0; j < 4; j++) needb = needb || (tmax[j] > m[j] + 7.f);
            const bool doresc = __any((int)needb);

            float cj[4], psum[4];
#pragma unroll
            for (int j = 0; j < 4; j++) {
                float mn = m[j];
                if (doresc) {
                    mn = fmaxf(m[j], tmax[j]);
                    cj[j] = __builtin_amdgcn_exp2f(m[j] - mn);
                    m[j] = mn;
                }
                float ps = 0.f;
#pragma unroll
                for (int ni = 0; ni < 4; ni++) {
                    const float e = __builtin_amdgcn_exp2f(p[ni][j] - mn);
                    p[ni][j] = e;
                    ps += e;
                }
                psum[j] = ps;
            }

            // ---- P -> bf16 via LDS transpose (overlaps the DPP sum) ----
#pragma unroll
            for (int ni = 0; ni < 4; ni++)
#pragma unroll
                for (int j = 0; j < 4; j++)
                    Pl[w][g * 4 + j][ni * 16 + lr] = (short)f2b(p[ni][j]);

#pragma unroll
            for (int j = 0; j < 4; j++) psum[j] = red16_sum(psum[j]);

            if (doresc) {
#pragma unroll
                for (int j = 0; j < 4; j++) lsum[j] = lsum[j] * cj[j] + psum[j];
#pragma unroll
                for (int di = 0; di < 8; di++)
#pragma unroll
                    for (int j = 0; j < 4; j++) oacc[di][j] *= cj[j];
            } else {
#pragma unroll
                for (int j = 0; j < 4; j++) lsum[j] += psum[j];
            }

            // ---- PV: O += P[16x64] @ V[64x128] ----
            __builtin_amdgcn_s_setprio(1);
#pragma unroll
            for (int kk = 0; kk < 2; kk++) {
                const s8v pa = *(const s8v*)&Pl[w][lr][kk * 32 + g * 8];
#pragma unroll
                for (int di = 0; di < 8; di++) {
                    const int r = di * 16 + lr;
                    const int ph = (kk * 4 + g) ^ (r & 7);
                    const s8v vb = *(const s8v*)&Vs[cur][r][ph * 8];
                    oacc[di] = MFMA(pa, vb, oacc[di]);
                }
            }
            __builtin_amdgcn_s_setprio(0);
            cur ^= 1;
        }

        // ---- epilogue: 1/l, sigmoid gate, store into qkv q-columns ----
        float linv[4];
#pragma unroll
        for (int j = 0; j < 4; j++) linv[j] = 1.f / lsum[j];
#pragma unroll
        for (int di = 0; di < 8; di++) {
            const int d = di * 16 + lr;
#pragma unroll
            for (int j = 0; j < 4; j++) {
                const int q = qw0 + g * 4 + j;
                const size_t base = (size_t)(b * S_ + q) * NQKV + h * 256;
                const float gate = b2f(qkv[base + 128 + d]);
                const float o = oacc[di][j] * linv[j] * (1.f / (1.f + __expf(-gate)));
                qkv[base + d] = (short)f2b(o);
            }
        }
    }
}

// ---------------------------------------------------------------------------
extern "C" void kernel_launch(void* const* d_in, const int* in_sizes, int n_in,
                              void* d_out, int out_size, void* d_ws, size_t ws_size,
                              hipStream_t stream) {
    const float* hs = (const float*)d_in[0];
    const float* cosb = (const float*)d_in[1];
    const float* sinb = (const float*)d_in[2];
    const float* Wq = (const float*)d_in[3];
    const float* Wk = (const float*)d_in[4];
    const float* Wv = (const float*)d_in[5];
    const float* Wo = (const float*)d_in[6];
    const float* qnw = (const float*)d_in[7];
    const float* knw = (const float*)d_in[8];
    float* out = (float*)d_out;

    short* ws = (short*)d_ws;
    short* Wot = ws;                  // 4194304
    short* Wt  = ws + 4194304;        // 12582912 (Wq^T rows 0..4095, Wk^T 4096.., Wv^T 5120..)
    short* hsb = ws + 16777216;       // 8388608
    short* qkv = ws + 25165824;       // 25165824  (total = 50331648 shorts = 96 MiB)
    // reuse after QKV gemm:
    short* qro = Wt;                  // 8388608
    short* kro = Wt + 8388608;        // 4194304
    short* vtb = hsb;                 // 4194304

    const int M = B_ * S_;
    const dim3 t32x8(32, 8, 1);

    // bf16 conversions / transposes
    f2bf_kernel<<<8192, 256, 0, stream>>>(hs, hsb, 2097152);
    transpose_conv<<<dim3(128, 64), t32x8, 0, stream>>>(Wq, Wt, HID_, 4096);
    transpose_conv<<<dim3(32, 64), t32x8, 0, stream>>>(Wk, Wt + (size_t)4096 * 2048, HID_, 1024);
    transpose_conv<<<dim3(32, 64), t32x8, 0, stream>>>(Wv, Wt + (size_t)5120 * 2048, HID_, 1024);
    transpose_conv<<<dim3(64, 64), t32x8, 0, stream>>>(Wo, Wot, 2048, 2048);

    // merged QKV projection (bf16 MFMA): qkv[M][6144]
    gemm_bt<short, 0><<<dim3(48, 32), 256, 0, stream>>>(hsb, Wt, qkv, M, NQKV, HID_);

    // RMSNorm + RoPE
    norm_rope<<<dim3(B_ * S_ * H_), 128, 0, stream>>>((const bf16*)qkv, qnw, cosb, sinb,
                                                      (bf16*)qro, H_, NQKV, 256);
    norm_rope<<<dim3(B_ * S_ * KVH_), 128, 0, stream>>>((const bf16*)(qkv + 4096), knw, cosb, sinb,
                                                        (bf16*)kro, KVH_, NQKV, 128);

    // V transpose to [head][D][S]
    transpose_v<<<dim3(64, 4, 16), t32x8, 0, stream>>>(qkv + 5120, vtb);

    // causal GQA attention + gate (writes into qkv q-columns), paired q-tiles
    flash_mfma<<<dim3(16, 32), 256, 0, stream>>>(qro, kro, vtb, qkv);

    // output projection (fp32 out), A read from qkv gated layout
    gemm_bt<float, 1><<<dim3(16, 32), 256, 0, stream>>>(qkv, Wot, out, M, HID_, 2048);
}

// Round 7
// 328.030 us; speedup vs baseline: 20.3925x; 1.0168x over previous
//
#include <hip/hip_runtime.h>
#include <hip/hip_bf16.h>

#define B_ 2
#define S_ 2048
#define HID_ 2048
#define H_ 16
#define KVH_ 8
#define D_ 128
#define G_ 2
#define EPS_ 1e-6f
#define SCALE_ 0.08838834764831845f
// SCALE * log2(e): scores computed directly in log2 domain
#define SCALE2_ 0.1275313760443445f
#define NQKV 6144

typedef __hip_bfloat16 bf16;
typedef __attribute__((ext_vector_type(8))) short s8v;   // 8 bf16 = 4 VGPR
typedef __attribute__((ext_vector_type(4))) float f4v;   // MFMA C/D

__device__ __forceinline__ unsigned short f2b(float f) {
    __hip_bfloat16 h = __float2bfloat16(f);
    return *reinterpret_cast<unsigned short*>(&h);
}
__device__ __forceinline__ float b2f(short u) {
    unsigned int x = ((unsigned int)(unsigned short)u) << 16;
    return __builtin_bit_cast(float, x);
}

__device__ __forceinline__ f4v MFMA(s8v a, s8v b, f4v c) {
    return __builtin_amdgcn_mfma_f32_16x16x32_bf16(a, b, c, 0, 0, 0);
}

__device__ __forceinline__ void gl_lds16(const void* g, void* l) {
    __builtin_amdgcn_global_load_lds(
        (const __attribute__((address_space(1))) void*)g,
        (__attribute__((address_space(3))) void*)l, 16, 0, 0);
}

__device__ __forceinline__ void cstore(float* p, float v) { *p = v; }
__device__ __forceinline__ void cstore(short* p, float v) { *p = (short)f2b(v); }

// ---- DPP 16-lane butterfly reduction (VALU, no LDS swizzle) ----
template <int CTRL>
__device__ __forceinline__ float dpp_f(float x) {
    return __builtin_bit_cast(float,
        __builtin_amdgcn_update_dpp(0, __builtin_bit_cast(int, x), CTRL, 0xF, 0xF, true));
}
__device__ __forceinline__ float red16_max(float v) {
    v = fmaxf(v, dpp_f<0xB1>(v));
    v = fmaxf(v, dpp_f<0x4E>(v));
    v = fmaxf(v, dpp_f<0x124>(v));
    v = fmaxf(v, dpp_f<0x128>(v));
    return v;
}
__device__ __forceinline__ float red16_sum(float v) {
    v += dpp_f<0xB1>(v);
    v += dpp_f<0x4E>(v);
    v += dpp_f<0x124>(v);
    v += dpp_f<0x128>(v);
    return v;
}

// ---------------------------------------------------------------------------
// fp32 -> bf16 bulk convert (vectorized)
// ---------------------------------------------------------------------------
__global__ __launch_bounds__(256) void f2bf_kernel(const float* __restrict__ in,
                                                   short* __restrict__ out, int n4) {
    int i = blockIdx.x * 256 + threadIdx.x;
    if (i >= n4) return;
    const float4 v = *(const float4*)(in + (size_t)i * 4);
    ushort4 o;
    o.x = f2b(v.x); o.y = f2b(v.y); o.z = f2b(v.z); o.w = f2b(v.w);
    *(ushort4*)(out + (size_t)i * 4) = o;
}

// ---------------------------------------------------------------------------
// W[K][N] fp32  ->  Wt[N][K] bf16   (32x32 LDS tile transpose)
// ---------------------------------------------------------------------------
__global__ __launch_bounds__(256) void transpose_conv(const float* __restrict__ in,
                                                      short* __restrict__ out,
                                                      int K, int N) {
    __shared__ short t[32][33];
    const int n0 = blockIdx.x * 32, k0 = blockIdx.y * 32;
    const int tx = threadIdx.x, ty = threadIdx.y;
#pragma unroll
    for (int j = 0; j < 4; j++) {
        const int r = ty + j * 8;
        t[r][tx] = (short)f2b(in[(size_t)(k0 + r) * N + n0 + tx]);
    }
    __syncthreads();
#pragma unroll
    for (int j = 0; j < 4; j++) {
        const int r = ty + j * 8;
        out[(size_t)(n0 + r) * K + k0 + tx] = t[tx][r];
    }
}

// ---------------------------------------------------------------------------
// V transpose per head: qkv v-columns -> vt[(b*KVH+kvh)][D][S]
// ---------------------------------------------------------------------------
__global__ __launch_bounds__(256) void transpose_v(const short* __restrict__ in,
                                                   short* __restrict__ out) {
    __shared__ short t[32][33];
    const int s0 = blockIdx.x * 32, d0 = blockIdx.y * 32, bk = blockIdx.z;
    const int b = bk / KVH_, kvh = bk % KVH_;
    const short* ip = in + (size_t)b * S_ * NQKV + kvh * D_;
    const int tx = threadIdx.x, ty = threadIdx.y;
#pragma unroll
    for (int j = 0; j < 4; j++) {
        const int r = ty + j * 8;
        t[r][tx] = ip[(size_t)(s0 + r) * NQKV + d0 + tx];
    }
    __syncthreads();
#pragma unroll
    for (int j = 0; j < 4; j++) {
        const int r = ty + j * 8;
        out[((size_t)bk * D_ + d0 + r) * S_ + s0 + tx] = t[tx][r];
    }
}

// ---------------------------------------------------------------------------
// MFMA GEMM (B^T form): C[M,N] = A[M,K] @ Bt[N,K]^T, bf16 in, fp32 acc.
// 128x128 tile, BK=32, 4 waves (2x2). Depth-2 counted-vmcnt pipeline:
// raw s_barrier (NO vmcnt(0) drain), prefetch loads stay in flight across
// barriers (T4). Per tile & wave: 4 global_load_lds insts -> vmcnt(4) waits
// for own tile-t loads while tile-t+1's 4 remain outstanding.
// Read-side XOR slot swizzle; bijective XCD blockid swizzle (nwg%8==0).
// GATED=1: A element (row,k) lives at row*NQKV + ((k>>7)<<8) + (k&127).
// ---------------------------------------------------------------------------
template <typename CT, int GATED>
__global__ __launch_bounds__(256) void gemm_bt(const short* __restrict__ A,
                                               const short* __restrict__ Bt,
                                               CT* __restrict__ C,
                                               int M, int N, int K) {
    __shared__ __align__(16) short As[2][128][32];
    __shared__ __align__(16) short Bs[2][128][32];
    const int tid = threadIdx.x;
    const int w = tid >> 6, l = tid & 63;
    const int lr = l & 15, g = l >> 4;
    const int nwg = gridDim.x * gridDim.y;
    int bid = blockIdx.y * gridDim.x + blockIdx.x;
    bid = (bid & 7) * (nwg >> 3) + (bid >> 3);
    const int bx = bid % gridDim.x, by = bid / gridDim.x;
    const int row0 = by * 128, col0 = bx * 128;
    const int wr = w >> 1, wc = w & 1;

    f4v acc[4][4];
#pragma unroll
    for (int i = 0; i < 4; i++)
#pragma unroll
        for (int j = 0; j < 4; j++) acc[i][j] = (f4v)0.f;

    const int srow = l >> 2;                       // row within 16-row chunk
    const int sg = (l & 3) ^ ((srow >> 1) & 3);    // swizzled source 16B chunk

    auto stage = [&](int buf, int kt) {
        const int k = kt + sg * 8;
#pragma unroll
        for (int i = 0; i < 2; i++) {
            const int rb = (w * 2 + i) * 16;
            size_t aoff;
            if constexpr (GATED)
                aoff = (size_t)(row0 + rb + srow) * NQKV + ((k >> 7) << 8) + (k & 127);
            else
                aoff = (size_t)(row0 + rb + srow) * K + k;
            gl_lds16(A + aoff, &As[buf][rb][0]);
            gl_lds16(Bt + (size_t)(col0 + rb + srow) * K + k, &Bs[buf][rb][0]);
        }
    };

    const int nt = K >> 5;           // BK=32 tiles; nt >= 2 required
    stage(0, 0);
    stage(1, 32);
    const int rdslot = (g ^ ((lr >> 1) & 3)) * 8;  // same for all frags

#pragma unroll 1
    for (int t = 0; t < nt; t++) {
        const int cur = t & 1;
        // tile t resident in LDS: own 4 loads done (t+1's 4 may still fly)
        if (t + 1 < nt) {
            asm volatile("s_waitcnt vmcnt(4)" ::: "memory");
        } else {
            asm volatile("s_waitcnt vmcnt(0)" ::: "memory");
        }
        __builtin_amdgcn_s_barrier();          // all waves' tile-t loads done
        __builtin_amdgcn_sched_barrier(0);

        s8v a[4], b[4];
#pragma unroll
        for (int mi = 0; mi < 4; mi++)
            a[mi] = *(const s8v*)&As[cur][wr * 64 + mi * 16 + lr][rdslot];
#pragma unroll
        for (int ni = 0; ni < 4; ni++)
            b[ni] = *(const s8v*)&Bs[cur][wc * 64 + ni * 16 + lr][rdslot];

        asm volatile("s_waitcnt lgkmcnt(0)" ::: "memory");  // my reads done
        __builtin_amdgcn_sched_barrier(0);
        __builtin_amdgcn_s_barrier();          // all waves done reading buf cur
        __builtin_amdgcn_sched_barrier(0);

        if (t + 2 < nt) stage(cur, (t + 2) * 32);  // refill freed buffer

#pragma unroll
        for (int mi = 0; mi < 4; mi++)
#pragma unroll
            for (int ni = 0; ni < 4; ni++)
                acc[mi][ni] = MFMA(a[mi], b[ni], acc[mi][ni]);
    }

#pragma unroll
    for (int mi = 0; mi < 4; mi++)
#pragma unroll
        for (int ni = 0; ni < 4; ni++) {
            const int row = row0 + wr * 64 + mi * 16 + g * 4;
            const int col = col0 + wc * 64 + ni * 16 + lr;
#pragma unroll
            for (int j = 0; j < 4; j++)
                cstore(&C[(size_t)(row + j) * N + col], acc[mi][ni][j]);
        }
}

// ---------------------------------------------------------------------------
// Per-(b,s,head) RMSNorm + RoPE (src row-strided for merged qkv buffer).
// ---------------------------------------------------------------------------
__global__ __launch_bounds__(128) void norm_rope(const bf16* __restrict__ src,
                                                 const float* __restrict__ normw,
                                                 const float* __restrict__ cosb,
                                                 const float* __restrict__ sinb,
                                                 bf16* __restrict__ dst,
                                                 int NH, int rowStride, int chanStride) {
    const int idx = blockIdx.x;
    const int h = idx % NH;
    const int s = (idx / NH) % S_;
    const int b = idx / (NH * S_);
    const int d = threadIdx.x;

    const size_t src_i = (size_t)(b * S_ + s) * rowStride + h * chanStride + d;
    const size_t dst_i = (((size_t)b * NH + h) * S_ + s) * D_ + d;

    float x = __bfloat162float(src[src_i]);
    float sq = x * x;
#pragma unroll
    for (int o = 32; o > 0; o >>= 1) sq += __shfl_down(sq, o);
    __shared__ float red[2];
    __shared__ float sh[128];
    if ((d & 63) == 0) red[d >> 6] = sq;
    __syncthreads();
    const float var = (red[0] + red[1]) * (1.f / 128.f);
    const float xn = x * rsqrtf(var + EPS_) * normw[d];
    sh[d] = xn;
    __syncthreads();
    const float rot = (d < 64) ? -sh[d + 64] : sh[d - 64];
    const size_t cs_i = ((size_t)b * S_ + s) * D_ + d;
    dst[dst_i] = __float2bfloat16(xn * cosb[cs_i] + rot * sinb[cs_i]);
}

// ---------------------------------------------------------------------------
// MFMA causal GQA flash attention + sigmoid gate.
// grid = (16, B*H), 256 thr. Each block processes TWO q-tiles {31-bx, bx}
// (33 KV-tile-iters each -> perfectly uniform load). 4 waves x 16 q-rows;
// KV tile = 64; 2-phase dbuf KV staging; DPP softmax in log2 domain with
// T13 defer-rescale; setprio around MFMA clusters.
// Gate read from qkv; output written into qkv's dead q-columns.
// ---------------------------------------------------------------------------
__global__ __launch_bounds__(256) void flash_mfma(const short* __restrict__ qro,
                                                  const short* __restrict__ kro,
                                                  const short* __restrict__ vt,
                                                  short* __restrict__ qkv) {
    __shared__ __align__(16) short Ks[2][64][128];   // [key][d], slot-swizzled
    __shared__ __align__(16) short Vs[2][128][64];   // [d][key], slot-swizzled
    __shared__ __align__(16) short Pl[4][16][84];    // per-wave P transpose

    const int tid = threadIdx.x;
    const int w = tid >> 6, l = tid & 63;
    const int lr = l & 15, g = l >> 4;
    const int bx = blockIdx.x;                       // 0..15
    const int bh = blockIdx.y;
    const int b = bh >> 4, h = bh & 15;
    const int kvh = h >> 1;

    const short* qbase = qro + (size_t)(b * H_ + h) * S_ * D_;
    const short* kbase = kro + (size_t)(b * KVH_ + kvh) * S_ * D_;
    const short* vbase = vt + (size_t)(b * KVH_ + kvh) * D_ * S_;

    auto stage = [&](int buf, int kt) {
        const int kb0 = kt * 64;
#pragma unroll
        for (int i = 0; i < 4; i++) {
            const int li = w * 4 + i;
            {
                const int r = li * 4 + (l >> 4);
                const int sgk = (l & 15) ^ (r & 7);
                gl_lds16(kbase + (size_t)(kb0 + r) * D_ + sgk * 8, &Ks[buf][li * 4][0]);
            }
            {
                const int r = li * 8 + (l >> 3);
                const int sgv = (l & 7) ^ (r & 7);
                gl_lds16(vbase + (size_t)r * S_ + kb0 + sgv * 8, &Vs[buf][li * 8][0]);
            }
        }
    };

#pragma unroll 1
    for (int seg = 0; seg < 2; seg++) {
        const int qt = seg ? bx : (31 - bx);         // heavy tile first
        const int q0 = qt * 64;
        const int qw0 = q0 + w * 16;

        if (seg) __syncthreads();                    // protect LDS reuse

        s8v qa[4];
#pragma unroll
        for (int kc = 0; kc < 4; kc++)
            qa[kc] = *(const s8v*)(qbase + (size_t)(qw0 + lr) * D_ + kc * 32 + g * 8);

        f4v oacc[8];
#pragma unroll
        for (int i = 0; i < 8; i++) oacc[i] = (f4v)0.f;
        float m[4] = {-3e38f, -3e38f, -3e38f, -3e38f};
        float lsum[4] = {0.f, 0.f, 0.f, 0.f};

        const int nkt = qt + 1;
        stage(0, 0);
        int cur = 0;
        for (int kt = 0; kt < nkt; kt++) {
            __syncthreads();
            if (kt + 1 < nkt) stage(cur ^ 1, kt + 1);
            const int kb0 = kt * 64;

            // ---- QK^T: S[16 q][64 keys] (log2 domain) ----
            f4v sacc[4];
#pragma unroll
            for (int ni = 0; ni < 4; ni++) sacc[ni] = (f4v)0.f;
            __builtin_amdgcn_s_setprio(1);
#pragma unroll
            for (int ni = 0; ni < 4; ni++) {
                const int r = ni * 16 + lr;
#pragma unroll
                for (int kc = 0; kc < 4; kc++) {
                    const int ph = (kc * 4 + g) ^ (r & 7);
                    const s8v kb = *(const s8v*)&Ks[cur][r][ph * 8];
                    sacc[ni] = MFMA(qa[kc], kb, sacc[ni]);
                }
            }
            __builtin_amdgcn_s_setprio(0);

            // ---- online softmax (log2), DPP reductions, defer-rescale ----
            const bool masked = (kt == qt);
            float p[4][4], tmax[4];
#pragma unroll
            for (int j = 0; j < 4; j++) {
                float v0 = -3e38f;
#pragma unroll
                for (int ni = 0; ni < 4; ni++) {
                    float sc = sacc[ni][j] * SCALE2_;
                    if (masked && (kb0 + ni * 16 + lr > qw0 + g * 4 + j)) sc = -3e38f;
                    p[ni][j] = sc;
                    v0 = fmaxf(v0, sc);
                }
                tmax[j] = v0;
            }
#pragma unroll
            for (int j = 0; j < 4; j++) tmax[j] = red16_max(tmax[j]);

            bool needb = false;
#pragma unroll
            for (int j = 0; j < 4; j++) needb = needb || (tmax[j] > m[j] + 7.f);
            const bool doresc = __any((int)needb);

            float cj[4], psum[4];
#pragma unroll
            for (int j = 0; j < 4; j++) {
                float mn = m[j];
                if (doresc) {
                    mn = fmaxf(m[j], tmax[j]);
                    cj[j] = __builtin_amdgcn_exp2f(m[j] - mn);
                    m[j] = mn;
                }
                float ps = 0.f;
#pragma unroll
                for (int ni = 0; ni < 4; ni++) {
                    const float e = __builtin_amdgcn_exp2f(p[ni][j] - mn);
                    p[ni][j] = e;
                    ps += e;
                }
                psum[j] = ps;
            }

            // ---- P -> bf16 via LDS transpose (overlaps the DPP sum) ----
#pragma unroll
            for (int ni = 0; ni < 4; ni++)
#pragma unroll
                for (int j = 0; j < 4; j++)
                    Pl[w][g * 4 + j][ni * 16 + lr] = (short)f2b(p[ni][j]);

#pragma unroll
            for (int j = 0; j < 4; j++) psum[j] = red16_sum(psum[j]);

            if (doresc) {
#pragma unroll
                for (int j = 0; j < 4; j++) lsum[j] = lsum[j] * cj[j] + psum[j];
#pragma unroll
                for (int di = 0; di < 8; di++)
#pragma unroll
                    for (int j = 0; j < 4; j++) oacc[di][j] *= cj[j];
            } else {
#pragma unroll
                for (int j = 0; j < 4; j++) lsum[j] += psum[j];
            }

            // ---- PV: O += P[16x64] @ V[64x128] ----
            __builtin_amdgcn_s_setprio(1);
#pragma unroll
            for (int kk = 0; kk < 2; kk++) {
                const s8v pa = *(const s8v*)&Pl[w][lr][kk * 32 + g * 8];
#pragma unroll
                for (int di = 0; di < 8; di++) {
                    const int r = di * 16 + lr;
                    const int ph = (kk * 4 + g) ^ (r & 7);
                    const s8v vb = *(const s8v*)&Vs[cur][r][ph * 8];
                    oacc[di] = MFMA(pa, vb, oacc[di]);
                }
            }
            __builtin_amdgcn_s_setprio(0);
            cur ^= 1;
        }

        // ---- epilogue: 1/l, sigmoid gate, store into qkv q-columns ----
        float linv[4];
#pragma unroll
        for (int j = 0; j < 4; j++) linv[j] = 1.f / lsum[j];
#pragma unroll
        for (int di = 0; di < 8; di++) {
            const int d = di * 16 + lr;
#pragma unroll
            for (int j = 0; j < 4; j++) {
                const int q = qw0 + g * 4 + j;
                const size_t base = (size_t)(b * S_ + q) * NQKV + h * 256;
                const float gate = b2f(qkv[base + 128 + d]);
                const float o = oacc[di][j] * linv[j] * (1.f / (1.f + __expf(-gate)));
                qkv[base + d] = (short)f2b(o);
            }
        }
    }
}

// ---------------------------------------------------------------------------
extern "C" void kernel_launch(void* const* d_in, const int* in_sizes, int n_in,
                              void* d_out, int out_size, void* d_ws, size_t ws_size,
                              hipStream_t stream) {
    const float* hs = (const float*)d_in[0];
    const float* cosb = (const float*)d_in[1];
    const float* sinb = (const float*)d_in[2];
    const float* Wq = (const float*)d_in[3];
    const float* Wk = (const float*)d_in[4];
    const float* Wv = (const float*)d_in[5];
    const float* Wo = (const float*)d_in[6];
    const float* qnw = (const float*)d_in[7];
    const float* knw = (const float*)d_in[8];
    float* out = (float*)d_out;

    short* ws = (short*)d_ws;
    short* Wot = ws;                  // 4194304
    short* Wt  = ws + 4194304;        // 12582912 (Wq^T rows 0..4095, Wk^T 4096.., Wv^T 5120..)
    short* hsb = ws + 16777216;       // 8388608
    short* qkv = ws + 25165824;       // 25165824  (total = 50331648 shorts = 96 MiB)
    // reuse after QKV gemm:
    short* qro = Wt;                  // 8388608
    short* kro = Wt + 8388608;        // 4194304
    short* vtb = hsb;                 // 4194304

    const int M = B_ * S_;
    const dim3 t32x8(32, 8, 1);

    // bf16 conversions / transposes
    f2bf_kernel<<<8192, 256, 0, stream>>>(hs, hsb, 2097152);
    transpose_conv<<<dim3(128, 64), t32x8, 0, stream>>>(Wq, Wt, HID_, 4096);
    transpose_conv<<<dim3(32, 64), t32x8, 0, stream>>>(Wk, Wt + (size_t)4096 * 2048, HID_, 1024);
    transpose_conv<<<dim3(32, 64), t32x8, 0, stream>>>(Wv, Wt + (size_t)5120 * 2048, HID_, 1024);
    transpose_conv<<<dim3(64, 64), t32x8, 0, stream>>>(Wo, Wot, 2048, 2048);

    // merged QKV projection (bf16 MFMA): qkv[M][6144]
    gemm_bt<short, 0><<<dim3(48, 32), 256, 0, stream>>>(hsb, Wt, qkv, M, NQKV, HID_);

    // RMSNorm + RoPE
    norm_rope<<<dim3(B_ * S_ * H_), 128, 0, stream>>>((const bf16*)qkv, qnw, cosb, sinb,
                                                      (bf16*)qro, H_, NQKV, 256);
    norm_rope<<<dim3(B_ * S_ * KVH_), 128, 0, stream>>>((const bf16*)(qkv + 4096), knw, cosb, sinb,
                                                        (bf16*)kro, KVH_, NQKV, 128);

    // V transpose to [head][D][S]
    transpose_v<<<dim3(64, 4, 16), t32x8, 0, stream>>>(qkv + 5120, vtb);

    // causal GQA attention + gate (writes into qkv q-columns), paired q-tiles
    flash_mfma<<<dim3(16, 32), 256, 0, stream>>>(qro, kro, vtb, qkv);

    // output projection (fp32 out), A read from qkv gated layout
    gemm_bt<float, 1><<<dim3(16, 32), 256, 0, stream>>>(qkv, Wot, out, M, HID_, 2048);
}

// Round 8
// 325.960 us; speedup vs baseline: 20.5219x; 1.0063x over previous
//
#include <hip/hip_runtime.h>
#include <hip/hip_bf16.h>

#define B_ 2
#define S_ 2048
#define HID_ 2048
#define H_ 16
#define KVH_ 8
#define D_ 128
#define G_ 2
#define EPS_ 1e-6f
#define SCALE_ 0.08838834764831845f
// SCALE * log2(e): scores computed directly in log2 domain
#define SCALE2_ 0.1275313760443445f
#define NQKV 6144

typedef __hip_bfloat16 bf16;
typedef __attribute__((ext_vector_type(8))) short s8v;   // 8 bf16 = 4 VGPR
typedef __attribute__((ext_vector_type(4))) float f4v;   // MFMA C/D

__device__ __forceinline__ unsigned short f2b(float f) {
    __hip_bfloat16 h = __float2bfloat16(f);
    return *reinterpret_cast<unsigned short*>(&h);
}
__device__ __forceinline__ float b2f(short u) {
    unsigned int x = ((unsigned int)(unsigned short)u) << 16;
    return __builtin_bit_cast(float, x);
}

__device__ __forceinline__ f4v MFMA(s8v a, s8v b, f4v c) {
    return __builtin_amdgcn_mfma_f32_16x16x32_bf16(a, b, c, 0, 0, 0);
}

__device__ __forceinline__ void gl_lds16(const void* g, void* l) {
    __builtin_amdgcn_global_load_lds(
        (const __attribute__((address_space(1))) void*)g,
        (__attribute__((address_space(3))) void*)l, 16, 0, 0);
}

__device__ __forceinline__ void cstore(float* p, float v) { *p = v; }
__device__ __forceinline__ void cstore(short* p, float v) { *p = (short)f2b(v); }

// ---- DPP 16-lane butterfly reduction (VALU, no LDS swizzle) ----
template <int CTRL>
__device__ __forceinline__ float dpp_f(float x) {
    return __builtin_bit_cast(float,
        __builtin_amdgcn_update_dpp(0, __builtin_bit_cast(int, x), CTRL, 0xF, 0xF, true));
}
__device__ __forceinline__ float red16_max(float v) {
    v = fmaxf(v, dpp_f<0xB1>(v));
    v = fmaxf(v, dpp_f<0x4E>(v));
    v = fmaxf(v, dpp_f<0x124>(v));
    v = fmaxf(v, dpp_f<0x128>(v));
    return v;
}
__device__ __forceinline__ float red16_sum(float v) {
    v += dpp_f<0xB1>(v);
    v += dpp_f<0x4E>(v);
    v += dpp_f<0x124>(v);
    v += dpp_f<0x128>(v);
    return v;
}

// ---------------------------------------------------------------------------
// fp32 -> bf16 bulk convert (vectorized)
// ---------------------------------------------------------------------------
__global__ __launch_bounds__(256) void f2bf_kernel(const float* __restrict__ in,
                                                   short* __restrict__ out, int n4) {
    int i = blockIdx.x * 256 + threadIdx.x;
    if (i >= n4) return;
    const float4 v = *(const float4*)(in + (size_t)i * 4);
    ushort4 o;
    o.x = f2b(v.x); o.y = f2b(v.y); o.z = f2b(v.z); o.w = f2b(v.w);
    *(ushort4*)(out + (size_t)i * 4) = o;
}

// ---------------------------------------------------------------------------
// W[K][N] fp32  ->  Wt[N][K] bf16   (32x32 LDS tile transpose)
// ---------------------------------------------------------------------------
__global__ __launch_bounds__(256) void transpose_conv(const float* __restrict__ in,
                                                      short* __restrict__ out,
                                                      int K, int N) {
    __shared__ short t[32][33];
    const int n0 = blockIdx.x * 32, k0 = blockIdx.y * 32;
    const int tx = threadIdx.x, ty = threadIdx.y;
#pragma unroll
    for (int j = 0; j < 4; j++) {
        const int r = ty + j * 8;
        t[r][tx] = (short)f2b(in[(size_t)(k0 + r) * N + n0 + tx]);
    }
    __syncthreads();
#pragma unroll
    for (int j = 0; j < 4; j++) {
        const int r = ty + j * 8;
        out[(size_t)(n0 + r) * K + k0 + tx] = t[tx][r];
    }
}

// ---------------------------------------------------------------------------
// V transpose per head: qkv v-columns -> vt[(b*KVH+kvh)][D][S]
// ---------------------------------------------------------------------------
__global__ __launch_bounds__(256) void transpose_v(const short* __restrict__ in,
                                                   short* __restrict__ out) {
    __shared__ short t[32][33];
    const int s0 = blockIdx.x * 32, d0 = blockIdx.y * 32, bk = blockIdx.z;
    const int b = bk / KVH_, kvh = bk % KVH_;
    const short* ip = in + (size_t)b * S_ * NQKV + kvh * D_;
    const int tx = threadIdx.x, ty = threadIdx.y;
#pragma unroll
    for (int j = 0; j < 4; j++) {
        const int r = ty + j * 8;
        t[r][tx] = ip[(size_t)(s0 + r) * NQKV + d0 + tx];
    }
    __syncthreads();
#pragma unroll
    for (int j = 0; j < 4; j++) {
        const int r = ty + j * 8;
        out[((size_t)bk * D_ + d0 + r) * S_ + s0 + tx] = t[tx][r];
    }
}

// ---------------------------------------------------------------------------
// 256x256 deep-pipelined MFMA GEMM (B^T form): C = A[M,K] @ Bt[N,K]^T.
// BK=32, 8 waves (2M x 4N), per-wave 128x64 output (8x4 frags).
// THREE LDS buffers (96 KB): loads for tile t+2 are issued during tile t
// -> issue-to-use distance ~2 K-tiles >= HBM latency.
// Invariant: each thread issues exactly 4 gl_lds per tile (2 A in phase 0,
// 2 B in phase 1). At tile-t top, s_waitcnt vmcnt(4) retires all loads
// except tile-(t+1)'s 4 -> tile t's data is resident. Never drains to 0
// in the main loop (T4). Raw s_barrier + sched_barrier(0) fences.
// Same XOR slot swizzle as the 128^2 kernel (measured 0 bank conflicts).
// ---------------------------------------------------------------------------
__global__ __launch_bounds__(512, 2) void gemm256(const short* __restrict__ A,
                                                  const short* __restrict__ Bt,
                                                  short* __restrict__ C,
                                                  int M, int N, int K) {
    __shared__ __align__(16) short As[3][256][32];   // 48 KB
    __shared__ __align__(16) short Bs[3][256][32];   // 48 KB
    const int tid = threadIdx.x;
    const int w = tid >> 6, l = tid & 63;
    const int lr = l & 15, g = l >> 4;
    const int nwg = gridDim.x * gridDim.y;
    int bid = blockIdx.y * gridDim.x + blockIdx.x;
    bid = (bid & 7) * (nwg >> 3) + (bid >> 3);       // XCD swizzle (nwg%8==0)
    const int bx = bid % gridDim.x, by = bid / gridDim.x;
    const int row0 = by * 256, col0 = bx * 256;
    const int wr = w >> 2, wc = w & 3;               // 2 x 4 wave grid

    f4v acc[8][4];
#pragma unroll
    for (int i = 0; i < 8; i++)
#pragma unroll
        for (int j = 0; j < 4; j++) acc[i][j] = (f4v)0.f;

    // staging: lane l covers row (l>>2), 16B chunk (l&3) of a 16-row stripe
    const int srow = l >> 2;
    const int schunk = (l & 3) ^ ((l >> 3) & 3);     // pre-swizzled source chunk
    const int rdslot = (g ^ ((lr >> 1) & 3)) * 8;    // swizzled read slot (elems)

    auto stageA = [&](int buf, int t) {
        const int kt = t * 32;
#pragma unroll
        for (int i = 0; i < 2; i++) {
            const int rb = w * 32 + i * 16;
            gl_lds16(A + (size_t)(row0 + rb + srow) * K + kt + schunk * 8,
                     &As[buf][rb][0]);
        }
    };
    auto stageB = [&](int buf, int t) {
        const int kt = t * 32;
#pragma unroll
        for (int i = 0; i < 2; i++) {
            const int rb = w * 32 + i * 16;
            gl_lds16(Bt + (size_t)(col0 + rb + srow) * K + kt + schunk * 8,
                     &Bs[buf][rb][0]);
        }
    };

    const int nt = K >> 5;                           // 64 tiles at K=2048
    stageA(0, 0); stageB(0, 0);                      // tile 0 -> buf 0
    stageA(1, 1); stageB(1, 1);                      // tile 1 -> buf 1

#pragma unroll 1
    for (int t = 0; t < nt; t++) {
        const int buf = t % 3;
        const int nbuf = (t + 2) % 3;

        // ---- tile-ready gate: all but tile-(t+1)'s 4 loads retired ----
        __builtin_amdgcn_sched_barrier(0);
        if (t + 1 < nt) {
            asm volatile("s_waitcnt vmcnt(4)" ::: "memory");
        } else {
            asm volatile("s_waitcnt vmcnt(0)" ::: "memory");
        }
        __builtin_amdgcn_sched_barrier(0);
        __builtin_amdgcn_s_barrier();
        __builtin_amdgcn_sched_barrier(0);

        // ---- phase 0: B frags + A rows 0-63, stage A of t+2, MFMA ----
        s8v b[4], a[4];
#pragma unroll
        for (int ni = 0; ni < 4; ni++)
            b[ni] = *(const s8v*)&Bs[buf][wc * 64 + ni * 16 + lr][rdslot];
#pragma unroll
        for (int mi = 0; mi < 4; mi++)
            a[mi] = *(const s8v*)&As[buf][wr * 128 + mi * 16 + lr][rdslot];
        if (t + 2 < nt) stageA(nbuf, t + 2);
        __builtin_amdgcn_s_setprio(1);
#pragma unroll
        for (int mi = 0; mi < 4; mi++)
#pragma unroll
            for (int ni = 0; ni < 4; ni++)
                acc[mi][ni] = MFMA(a[mi], b[ni], acc[mi][ni]);
        __builtin_amdgcn_s_setprio(0);
        __builtin_amdgcn_s_barrier();
        __builtin_amdgcn_sched_barrier(0);

        // ---- phase 1: A rows 64-127, stage B of t+2, MFMA ----
        s8v a2[4];
#pragma unroll
        for (int mi = 0; mi < 4; mi++)
            a2[mi] = *(const s8v*)&As[buf][wr * 128 + (4 + mi) * 16 + lr][rdslot];
        if (t + 2 < nt) stageB(nbuf, t + 2);
        __builtin_amdgcn_s_setprio(1);
#pragma unroll
        for (int mi = 0; mi < 4; mi++)
#pragma unroll
            for (int ni = 0; ni < 4; ni++)
                acc[4 + mi][ni] = MFMA(a2[mi], b[ni], acc[4 + mi][ni]);
        __builtin_amdgcn_s_setprio(0);
        // no trailing barrier: next tile's top gate covers the buf rotation
    }

#pragma unroll
    for (int mi = 0; mi < 8; mi++)
#pragma unroll
        for (int ni = 0; ni < 4; ni++) {
            const int row = row0 + wr * 128 + mi * 16 + g * 4;
            const int col = col0 + wc * 64 + ni * 16 + lr;
#pragma unroll
            for (int j = 0; j < 4; j++)
                cstore(&C[(size_t)(row + j) * N + col], acc[mi][ni][j]);
        }
}

// ---------------------------------------------------------------------------
// MFMA GEMM (B^T form), 128x128 tile, depth-2 counted-vmcnt (kept for Wo:
// its 256^2 grid would be only 128 blocks -> half the CUs idle).
// GATED=1: A element (row,k) lives at row*NQKV + ((k>>7)<<8) + (k&127).
// ---------------------------------------------------------------------------
template <typename CT, int GATED>
__global__ __launch_bounds__(256) void gemm_bt(const short* __restrict__ A,
                                               const short* __restrict__ Bt,
                                               CT* __restrict__ C,
                                               int M, int N, int K) {
    __shared__ __align__(16) short As[2][128][32];
    __shared__ __align__(16) short Bs[2][128][32];
    const int tid = threadIdx.x;
    const int w = tid >> 6, l = tid & 63;
    const int lr = l & 15, g = l >> 4;
    const int nwg = gridDim.x * gridDim.y;
    int bid = blockIdx.y * gridDim.x + blockIdx.x;
    bid = (bid & 7) * (nwg >> 3) + (bid >> 3);
    const int bx = bid % gridDim.x, by = bid / gridDim.x;
    const int row0 = by * 128, col0 = bx * 128;
    const int wr = w >> 1, wc = w & 1;

    f4v acc[4][4];
#pragma unroll
    for (int i = 0; i < 4; i++)
#pragma unroll
        for (int j = 0; j < 4; j++) acc[i][j] = (f4v)0.f;

    const int srow = l >> 2;                       // row within 16-row chunk
    const int sg = (l & 3) ^ ((srow >> 1) & 3);    // swizzled source 16B chunk

    auto stage = [&](int buf, int kt) {
        const int k = kt + sg * 8;
#pragma unroll
        for (int i = 0; i < 2; i++) {
            const int rb = (w * 2 + i) * 16;
            size_t aoff;
            if constexpr (GATED)
                aoff = (size_t)(row0 + rb + srow) * NQKV + ((k >> 7) << 8) + (k & 127);
            else
                aoff = (size_t)(row0 + rb + srow) * K + k;
            gl_lds16(A + aoff, &As[buf][rb][0]);
            gl_lds16(Bt + (size_t)(col0 + rb + srow) * K + k, &Bs[buf][rb][0]);
        }
    };

    const int nt = K >> 5;           // BK=32 tiles; nt >= 2 required
    stage(0, 0);
    stage(1, 32);
    const int rdslot = (g ^ ((lr >> 1) & 3)) * 8;  // same for all frags

#pragma unroll 1
    for (int t = 0; t < nt; t++) {
        const int cur = t & 1;
        if (t + 1 < nt) {
            asm volatile("s_waitcnt vmcnt(4)" ::: "memory");
        } else {
            asm volatile("s_waitcnt vmcnt(0)" ::: "memory");
        }
        __builtin_amdgcn_s_barrier();          // all waves' tile-t loads done
        __builtin_amdgcn_sched_barrier(0);

        s8v a[4], b[4];
#pragma unroll
        for (int mi = 0; mi < 4; mi++)
            a[mi] = *(const s8v*)&As[cur][wr * 64 + mi * 16 + lr][rdslot];
#pragma unroll
        for (int ni = 0; ni < 4; ni++)
            b[ni] = *(const s8v*)&Bs[cur][wc * 64 + ni * 16 + lr][rdslot];

        asm volatile("s_waitcnt lgkmcnt(0)" ::: "memory");  // my reads done
        __builtin_amdgcn_sched_barrier(0);
        __builtin_amdgcn_s_barrier();          // all waves done reading buf cur
        __builtin_amdgcn_sched_barrier(0);

        if (t + 2 < nt) stage(cur, (t + 2) * 32);  // refill freed buffer

#pragma unroll
        for (int mi = 0; mi < 4; mi++)
#pragma unroll
            for (int ni = 0; ni < 4; ni++)
                acc[mi][ni] = MFMA(a[mi], b[ni], acc[mi][ni]);
    }

#pragma unroll
    for (int mi = 0; mi < 4; mi++)
#pragma unroll
        for (int ni = 0; ni < 4; ni++) {
            const int row = row0 + wr * 64 + mi * 16 + g * 4;
            const int col = col0 + wc * 64 + ni * 16 + lr;
#pragma unroll
            for (int j = 0; j < 4; j++)
                cstore(&C[(size_t)(row + j) * N + col], acc[mi][ni][j]);
        }
}

// ---------------------------------------------------------------------------
// Per-(b,s,head) RMSNorm + RoPE (src row-strided for merged qkv buffer).
// ---------------------------------------------------------------------------
__global__ __launch_bounds__(128) void norm_rope(const bf16* __restrict__ src,
                                                 const float* __restrict__ normw,
                                                 const float* __restrict__ cosb,
                                                 const float* __restrict__ sinb,
                                                 bf16* __restrict__ dst,
                                                 int NH, int rowStride, int chanStride) {
    const int idx = blockIdx.x;
    const int h = idx % NH;
    const int s = (idx / NH) % S_;
    const int b = idx / (NH * S_);
    const int d = threadIdx.x;

    const size_t src_i = (size_t)(b * S_ + s) * rowStride + h * chanStride + d;
    const size_t dst_i = (((size_t)b * NH + h) * S_ + s) * D_ + d;

    float x = __bfloat162float(src[src_i]);
    float sq = x * x;
#pragma unroll
    for (int o = 32; o > 0; o >>= 1) sq += __shfl_down(sq, o);
    __shared__ float red[2];
    __shared__ float sh[128];
    if ((d & 63) == 0) red[d >> 6] = sq;
    __syncthreads();
    const float var = (red[0] + red[1]) * (1.f / 128.f);
    const float xn = x * rsqrtf(var + EPS_) * normw[d];
    sh[d] = xn;
    __syncthreads();
    const float rot = (d < 64) ? -sh[d + 64] : sh[d - 64];
    const size_t cs_i = ((size_t)b * S_ + s) * D_ + d;
    dst[dst_i] = __float2bfloat16(xn * cosb[cs_i] + rot * sinb[cs_i]);
}

// ---------------------------------------------------------------------------
// MFMA causal GQA flash attention + sigmoid gate.
// grid = (16, B*H), 256 thr. Each block processes TWO q-tiles {31-bx, bx}
// (33 KV-tile-iters each -> perfectly uniform load). 4 waves x 16 q-rows;
// KV tile = 64; 2-phase dbuf KV staging; DPP softmax in log2 domain with
// T13 defer-rescale; setprio around MFMA clusters.
// Gate read from qkv; output written into qkv's dead q-columns.
// ---------------------------------------------------------------------------
__global__ __launch_bounds__(256) void flash_mfma(const short* __restrict__ qro,
                                                  const short* __restrict__ kro,
                                                  const short* __restrict__ vt,
                                                  short* __restrict__ qkv) {
    __shared__ __align__(16) short Ks[2][64][128];   // [key][d], slot-swizzled
    __shared__ __align__(16) short Vs[2][128][64];   // [d][key], slot-swizzled
    __shared__ __align__(16) short Pl[4][16][84];    // per-wave P transpose

    const int tid = threadIdx.x;
    const int w = tid >> 6, l = tid & 63;
    const int lr = l & 15, g = l >> 4;
    const int bx = blockIdx.x;                       // 0..15
    const int bh = blockIdx.y;
    const int b = bh >> 4, h = bh & 15;
    const int kvh = h >> 1;

    const short* qbase = qro + (size_t)(b * H_ + h) * S_ * D_;
    const short* kbase = kro + (size_t)(b * KVH_ + kvh) * S_ * D_;
    const short* vbase = vt + (size_t)(b * KVH_ + kvh) * D_ * S_;

    auto stage = [&](int buf, int kt) {
        const int kb0 = kt * 64;
#pragma unroll
        for (int i = 0; i < 4; i++) {
            const int li = w * 4 + i;
            {
                const int r = li * 4 + (l >> 4);
                const int sgk = (l & 15) ^ (r & 7);
                gl_lds16(kbase + (size_t)(kb0 + r) * D_ + sgk * 8, &Ks[buf][li * 4][0]);
            }
            {
                const int r = li * 8 + (l >> 3);
                const int sgv = (l & 7) ^ (r & 7);
                gl_lds16(vbase + (size_t)r * S_ + kb0 + sgv * 8, &Vs[buf][li * 8][0]);
            }
        }
    };

#pragma unroll 1
    for (int seg = 0; seg < 2; seg++) {
        const int qt = seg ? bx : (31 - bx);         // heavy tile first
        const int q0 = qt * 64;
        const int qw0 = q0 + w * 16;

        if (seg) __syncthreads();                    // protect LDS reuse

        s8v qa[4];
#pragma unroll
        for (int kc = 0; kc < 4; kc++)
            qa[kc] = *(const s8v*)(qbase + (size_t)(qw0 + lr) * D_ + kc * 32 + g * 8);

        f4v oacc[8];
#pragma unroll
        for (int i = 0; i < 8; i++) oacc[i] = (f4v)0.f;
        float m[4] = {-3e38f, -3e38f, -3e38f, -3e38f};
        float lsum[4] = {0.f, 0.f, 0.f, 0.f};

        const int nkt = qt + 1;
        stage(0, 0);
        int cur = 0;
        for (int kt = 0; kt < nkt; kt++) {
            __syncthreads();
            if (kt + 1 < nkt) stage(cur ^ 1, kt + 1);
            const int kb0 = kt * 64;

            // ---- QK^T: S[16 q][64 keys] (log2 domain) ----
            f4v sacc[4];
#pragma unroll
            for (int ni = 0; ni < 4; ni++) sacc[ni] = (f4v)0.f;
            __builtin_amdgcn_s_setprio(1);
#pragma unroll
            for (int ni = 0; ni < 4; ni++) {
                const int r = ni * 16 + lr;
#pragma unroll
                for (int kc = 0; kc < 4; kc++) {
                    const int ph = (kc * 4 + g) ^ (r & 7);
                    const s8v kb = *(const s8v*)&Ks[cur][r][ph * 8];
                    sacc[ni] = MFMA(qa[kc], kb, sacc[ni]);
                }
            }
            __builtin_amdgcn_s_setprio(0);

            // ---- online softmax (log2), DPP reductions, defer-rescale ----
            const bool masked = (kt == qt);
            float p[4][4], tmax[4];
#pragma unroll
            for (int j = 0; j < 4; j++) {
                float v0 = -3e38f;
#pragma unroll
                for (int ni = 0; ni < 4; ni++) {
                    float sc = sacc[ni][j] * SCALE2_;
                    if (masked && (kb0 + ni * 16 + lr > qw0 + g * 4 + j)) sc = -3e38f;
                    p[ni][j] = sc;
                    v0 = fmaxf(v0, sc);
                }
                tmax[j] = v0;
            }
#pragma unroll
            for (int j = 0; j < 4; j++) tmax[j] = red16_max(tmax[j]);

            bool needb = false;
#pragma unroll
            for (int j = 0; j < 4; j++) needb = needb || (tmax[j] > m[j] + 7.f);
            const bool doresc = __any((int)needb);

            float cj[4], psum[4];
#pragma unroll
            for (int j = 0; j < 4; j++) {
                float mn = m[j];
                if (doresc) {
                    mn = fmaxf(m[j], tmax[j]);
                    cj[j] = __builtin_amdgcn_exp2f(m[j] - mn);
                    m[j] = mn;
                }
                float ps = 0.f;
#pragma unroll
                for (int ni = 0; ni < 4; ni++) {
                    const float e = __builtin_amdgcn_exp2f(p[ni][j] - mn);
                    p[ni][j] = e;
                    ps += e;
                }
                psum[j] = ps;
            }

            // ---- P -> bf16 via LDS transpose (overlaps the DPP sum) ----
#pragma unroll
            for (int ni = 0; ni < 4; ni++)
#pragma unroll
                for (int j = 0; j < 4; j++)
                    Pl[w][g * 4 + j][ni * 16 + lr] = (short)f2b(p[ni][j]);

#pragma unroll
            for (int j = 0; j < 4; j++) psum[j] = red16_sum(psum[j]);

            if (doresc) {
#pragma unroll
                for (int j = 0; j < 4; j++) lsum[j] = lsum[j] * cj[j] + psum[j];
#pragma unroll
                for (int di = 0; di < 8; di++)
#pragma unroll
                    for (int j = 0; j < 4; j++) oacc[di][j] *= cj[j];
            } else {
#pragma unroll
                for (int j = 0; j < 4; j++) lsum[j] += psum[j];
            }

            // ---- PV: O += P[16x64] @ V[64x128] ----
            __builtin_amdgcn_s_setprio(1);
#pragma unroll
            for (int kk = 0; kk < 2; kk++) {
                const s8v pa = *(const s8v*)&Pl[w][lr][kk * 32 + g * 8];
#pragma unroll
                for (int di = 0; di < 8; di++) {
                    const int r = di * 16 + lr;
                    const int ph = (kk * 4 + g) ^ (r & 7);
                    const s8v vb = *(const s8v*)&Vs[cur][r][ph * 8];
                    oacc[di] = MFMA(pa, vb, oacc[di]);
                }
            }
            __builtin_amdgcn_s_setprio(0);
            cur ^= 1;
        }

        // ---- epilogue: 1/l, sigmoid gate, store into qkv q-columns ----
        float linv[4];
#pragma unroll
        for (int j = 0; j < 4; j++) linv[j] = 1.f / lsum[j];
#pragma unroll
        for (int di = 0; di < 8; di++) {
            const int d = di * 16 + lr;
#pragma unroll
            for (int j = 0; j < 4; j++) {
                const int q = qw0 + g * 4 + j;
                const size_t base = (size_t)(b * S_ + q) * NQKV + h * 256;
                const float gate = b2f(qkv[base + 128 + d]);
                const float o = oacc[di][j] * linv[j] * (1.f / (1.f + __expf(-gate)));
                qkv[base + d] = (short)f2b(o);
            }
        }
    }
}

// ---------------------------------------------------------------------------
extern "C" void kernel_launch(void* const* d_in, const int* in_sizes, int n_in,
                              void* d_out, int out_size, void* d_ws, size_t ws_size,
                              hipStream_t stream) {
    const float* hs = (const float*)d_in[0];
    const float* cosb = (const float*)d_in[1];
    const float* sinb = (const float*)d_in[2];
    const float* Wq = (const float*)d_in[3];
    const float* Wk = (const float*)d_in[4];
    const float* Wv = (const float*)d_in[5];
    const float* Wo = (const float*)d_in[6];
    const float* qnw = (const float*)d_in[7];
    const float* knw = (const float*)d_in[8];
    float* out = (float*)d_out;

    short* ws = (short*)d_ws;
    short* Wot = ws;                  // 4194304
    short* Wt  = ws + 4194304;        // 12582912 (Wq^T rows 0..4095, Wk^T 4096.., Wv^T 5120..)
    short* hsb = ws + 16777216;       // 8388608
    short* qkv = ws + 25165824;       // 25165824  (total = 50331648 shorts = 96 MiB)
    // reuse after QKV gemm:
    short* qro = Wt;                  // 8388608
    short* kro = Wt + 8388608;        // 4194304
    short* vtb = hsb;                 // 4194304

    const int M = B_ * S_;
    const dim3 t32x8(32, 8, 1);

    // bf16 conversions / transposes
    f2bf_kernel<<<8192, 256, 0, stream>>>(hs, hsb, 2097152);
    transpose_conv<<<dim3(128, 64), t32x8, 0, stream>>>(Wq, Wt, HID_, 4096);
    transpose_conv<<<dim3(32, 64), t32x8, 0, stream>>>(Wk, Wt + (size_t)4096 * 2048, HID_, 1024);
    transpose_conv<<<dim3(32, 64), t32x8, 0, stream>>>(Wv, Wt + (size_t)5120 * 2048, HID_, 1024);
    transpose_conv<<<dim3(64, 64), t32x8, 0, stream>>>(Wo, Wot, 2048, 2048);

    // merged QKV projection: 256^2 deep-pipelined MFMA GEMM, qkv[M][6144]
    gemm256<<<dim3(24, 16), 512, 0, stream>>>(hsb, Wt, qkv, M, NQKV, HID_);

    // RMSNorm + RoPE
    norm_rope<<<dim3(B_ * S_ * H_), 128, 0, stream>>>((const bf16*)qkv, qnw, cosb, sinb,
                                                      (bf16*)qro, H_, NQKV, 256);
    norm_rope<<<dim3(B_ * S_ * KVH_), 128, 0, stream>>>((const bf16*)(qkv + 4096), knw, cosb, sinb,
                                                        (bf16*)kro, KVH_, NQKV, 128);

    // V transpose to [head][D][S]
    transpose_v<<<dim3(64, 4, 16), t32x8, 0, stream>>>(qkv + 5120, vtb);

    // causal GQA attention + gate (writes into qkv q-columns), paired q-tiles
    flash_mfma<<<dim3(16, 32), 256, 0, stream>>>(qro, kro, vtb, qkv);

    // output projection (fp32 out), A read from qkv gated layout
    gemm_bt<float, 1><<<dim3(16, 32), 256, 0, stream>>>(qkv, Wot, out, M, HID_, 2048);
}